// Round 2
// baseline (934.126 us; speedup 1.0000x reference)
//
#include <hip/hip_runtime.h>

// Dims: B=4, T=16, N=128, D=16, H=64, MH=128, 15 steps. NBLK=512 persistent blocks.
#define NBLK 512

// ---- workspace float offsets ----
#define OFF_A    0        // A_sym: 65536
#define OFF_HS   65536    // hs ping-pong: 2*65536
#define OFF_HR   196608   // hr ping-pong: 2*65536
#define OFF_HIST 327680   // hidden history: 15*512*64 = 491520
#define OFF_PART 819200   // 512 mse partials
#define OFF_BAR  819712   // 32 ints (count@0, gen@16)
#define OFF_BF   819744   // bf16 weights: 49152 ushorts

// ---- bf16 (ushort) offsets within bf area ----
#define BW2F 0        // W_msg2 B-frags: 16*64*8 = 8192
#define BWIR 8192
#define BWII 9216
#define BWIN 10240
#define BWHR 11264
#define BWHI 15360
#define BWHH 19456
#define BWO1 23552
#define BWO2 27648
#define BWO3 31744
#define BW1S 32768    // W1s | W1r : 16384

#define INIT_TOTAL 245792

typedef __attribute__((ext_vector_type(8))) __bf16 bf16x8;
typedef __attribute__((ext_vector_type(4))) float f32x4;
union frag_u { bf16x8 v; unsigned short s[8]; int4 q; };

__device__ __forceinline__ unsigned short f2b(float x) {
  unsigned int u = __float_as_uint(x);
  u += 0x7fffu + ((u >> 16) & 1u);
  return (unsigned short)(u >> 16);
}
__device__ __forceinline__ float b2f(unsigned short u) {
  return __uint_as_float(((unsigned int)u) << 16);
}
__device__ __forceinline__ float fast_tanh(float x) {
  float e = __builtin_amdgcn_exp2f(x * 2.8853900817779268f);
  return 1.0f - 2.0f * __builtin_amdgcn_rcpf(e + 1.0f);
}
__device__ __forceinline__ float fast_sigmoid(float x) {
  float e = __builtin_amdgcn_exp2f(x * -1.4426950408889634f);
  return __builtin_amdgcn_rcpf(1.0f + e);
}

// ---------------- init ----------------
__global__ void init_kernel(const float* __restrict__ A, const float* __restrict__ b_msg1,
                            const float* __restrict__ W_msg2,
                            const float* __restrict__ W_ir, const float* __restrict__ W_ii,
                            const float* __restrict__ W_in,
                            const float* __restrict__ W_hr, const float* __restrict__ W_hi,
                            const float* __restrict__ W_hh,
                            const float* __restrict__ W_o1, const float* __restrict__ W_o2,
                            const float* __restrict__ W_o3,
                            const float* __restrict__ W_msg1, float* __restrict__ ws) {
  int idx = blockIdx.x * 256 + threadIdx.x;
  unsigned short* bw = (unsigned short*)(ws + OFF_BF);
  if (idx < 65536) {
    int b = idx >> 14, rem = idx & 16383, i = rem >> 7, jj = rem & 127;
    float a  = A[idx];
    float at = A[(b << 14) + (jj << 7) + i];
    float v = 0.5f * (a + at);
    v = (i == jj) ? 0.0f : v;
    ws[OFF_A + idx] = fminf(fmaxf(v, 0.0f), 1.0f);
    return;
  }
  idx -= 65536;
  if (idx < 65536) { ws[OFF_HS + idx] = 0.0f; return; }
  idx -= 65536;
  if (idx < 65536) { ws[OFF_HR + idx] = b_msg1[idx & 127]; return; }
  idx -= 65536;
  if (idx < 32) { ((int*)(ws + OFF_BAR))[idx] = 0; return; }
  idx -= 32;
  if (idx < 8192) {  // W_msg2 B-frags
    int f = idx >> 9, l = (idx >> 3) & 63, jj = idx & 7;
    int kc = f >> 2, nt = f & 3;
    int k = kc * 32 + ((l >> 4) << 3) + jj;
    int n = (nt << 4) + (l & 15);
    bw[BW2F + idx] = f2b(W_msg2[k * 64 + n]);
    return;
  }
  idx -= 8192;
  if (idx < 1024) { bw[BWIR + idx] = f2b(W_ir[idx]); return; }
  idx -= 1024;
  if (idx < 1024) { bw[BWII + idx] = f2b(W_ii[idx]); return; }
  idx -= 1024;
  if (idx < 1024) { bw[BWIN + idx] = f2b(W_in[idx]); return; }
  idx -= 1024;
  if (idx < 4096) { bw[BWHR + idx] = f2b(W_hr[idx]); return; }
  idx -= 4096;
  if (idx < 4096) { bw[BWHI + idx] = f2b(W_hi[idx]); return; }
  idx -= 4096;
  if (idx < 4096) { bw[BWHH + idx] = f2b(W_hh[idx]); return; }
  idx -= 4096;
  if (idx < 4096) { bw[BWO1 + idx] = f2b(W_o1[idx]); return; }
  idx -= 4096;
  if (idx < 4096) { bw[BWO2 + idx] = f2b(W_o2[idx]); return; }
  idx -= 4096;
  if (idx < 1024) { bw[BWO3 + idx] = f2b(W_o3[idx]); return; }
  idx -= 1024;
  if (idx < 16384) { bw[BW1S + idx] = f2b(W_msg1[idx]); return; }
}

// ---------------- grid barrier (all 512 blocks co-resident by construction) ----------------
__device__ __forceinline__ void grid_barrier(int* bar_count, int* bar_gen, int target) {
  __syncthreads();
  if (threadIdx.x == 0) {
    __threadfence();  // release: drain + wbl2 so other XCDs can see our hs/hr stores
    int old = atomicAdd(bar_count, 1);
    if (old == NBLK - 1) {
      __hip_atomic_store(bar_count, 0, __ATOMIC_RELAXED, __HIP_MEMORY_SCOPE_AGENT);
      __hip_atomic_store(bar_gen, target, __ATOMIC_RELEASE, __HIP_MEMORY_SCOPE_AGENT);
    } else {
      while (__hip_atomic_load(bar_gen, __ATOMIC_ACQUIRE, __HIP_MEMORY_SCOPE_AGENT) < target)
        __builtin_amdgcn_s_sleep(2);
    }
    __threadfence();  // acquire: invalidate L1/L2 so plain loads see fresh data
  }
  __syncthreads();
}

// ---------------- persistent: all 15 steps ----------------
__launch_bounds__(256, 2)
__global__ void step_all_kernel(const float* __restrict__ X,
                                const float* __restrict__ b_msg1, const float* __restrict__ b_msg2,
                                const float* __restrict__ b_ir, const float* __restrict__ b_ii,
                                const float* __restrict__ b_in,
                                float* __restrict__ ws) {
  const int tid = threadIdx.x;
  const int bj = blockIdx.x;
  const int b = bj >> 7, j = bj & 127;
  const int wave = tid >> 6, lane = tid & 63;
  const unsigned short* bw = (const unsigned short*)(ws + OFF_BF);
  int* bar_count = (int*)(ws + OFF_BAR);
  int* bar_gen   = (int*)(ws + OFF_BAR) + 16;

  __shared__ unsigned short lds_gate[12288];  // W_hr@0 | W_hi@4096 | W_hh@8192
  __shared__ unsigned short lds_w1[16384];    // W1s@0 | W1r@8192
  __shared__ __align__(16) float sh_hr[128];
  __shared__ __align__(16) float sh_Ar[128];
  __shared__ float sh_aggw[4][64];
  __shared__ float sh_agg[64];
  __shared__ float sh_x[16];
  __shared__ float sh_hid[64];
  __shared__ float sh_pre[4][64];  // pre_r | pre_i | hh | pre_nx

  // ---- one-time staging ----
  {
    const int4* src = (const int4*)(bw + BWHR);   // 12288 ushorts = 1536 int4
    int4* dst = (int4*)lds_gate;
    for (int i = tid; i < 1536; i += 256) dst[i] = src[i];
    const int4* s2 = (const int4*)(bw + BW1S);    // 16384 ushorts = 2048 int4
    int4* d2 = (int4*)lds_w1;
    for (int i = tid; i < 2048; i += 256) d2[i] = s2[i];
  }
  if (tid < 128) sh_Ar[tid] = ws[OFF_A + (b << 14) + (j << 7) + tid];
  if (tid < 64) sh_hid[tid] = 0.0f;

  // persistent register state
  frag_u Bf[16];
  const int4* bw2 = (const int4*)bw;  // BW2F == 0
#pragma unroll
  for (int f = 0; f < 16; ++f) Bf[f].q = bw2[f * 64 + lane];
  float b2v[4];
#pragma unroll
  for (int nt = 0; nt < 4; ++nt) b2v[nt] = b_msg2[nt * 16 + (lane & 15)];
  float my_bias = 0.0f;
  if (wave == 0) my_bias = b_ir[lane];
  else if (wave == 1) my_bias = b_ii[lane];
  else if (wave == 3) my_bias = b_in[lane];
  float my_bmsg1 = (tid >= 128) ? b_msg1[tid - 128] : 0.0f;

  for (int t = 0; t < 15; ++t) {
    const int par = t & 1;
    const float* hs_cur = ws + OFF_HS + par * 65536;
    const float* hr_cur = ws + OFF_HR + par * 65536;
    float* hs_nxt = ws + OFF_HS + (par ^ 1) * 65536;
    float* hr_nxt = ws + OFF_HR + (par ^ 1) * 65536;

    if (tid < 128) sh_hr[tid] = hr_cur[(bj << 7) + tid];
    else if (tid < 144) sh_x[tid - 128] = X[(((b << 4) + t) << 11) + (j << 4) + (tid - 128)];
    __syncthreads();

    // ---- phase 2: agg ----
    float part[4] = {0.f, 0.f, 0.f, 0.f};
    const int k0 = (lane >> 4) << 3;
#pragma unroll
    for (int c = 0; c < 2; ++c) {
      const int ibase = ((wave << 1) + c) << 4;
      const int irow = ibase + (lane & 15);
      const float* hsrow = hs_cur + (((b << 7) + irow) << 7);
      f32x4 acc[4];
#pragma unroll
      for (int nt = 0; nt < 4; ++nt) acc[nt] = (f32x4){0.f, 0.f, 0.f, 0.f};
#pragma unroll
      for (int kc = 0; kc < 4; ++kc) {
        const int kk = kc * 32 + k0;
        float4 a0 = *(const float4*)(hsrow + kk);
        float4 a1 = *(const float4*)(hsrow + kk + 4);
        float4 h0 = *(const float4*)(sh_hr + kk);
        float4 h1 = *(const float4*)(sh_hr + kk + 4);
        frag_u Af;
        Af.s[0] = f2b(fast_tanh(a0.x + h0.x));
        Af.s[1] = f2b(fast_tanh(a0.y + h0.y));
        Af.s[2] = f2b(fast_tanh(a0.z + h0.z));
        Af.s[3] = f2b(fast_tanh(a0.w + h0.w));
        Af.s[4] = f2b(fast_tanh(a1.x + h1.x));
        Af.s[5] = f2b(fast_tanh(a1.y + h1.y));
        Af.s[6] = f2b(fast_tanh(a1.z + h1.z));
        Af.s[7] = f2b(fast_tanh(a1.w + h1.w));
#pragma unroll
        for (int nt = 0; nt < 4; ++nt)
          acc[nt] = __builtin_amdgcn_mfma_f32_16x16x32_bf16(Af.v, Bf[kc * 4 + nt].v, acc[nt], 0, 0, 0);
      }
      float4 aw = *(const float4*)(sh_Ar + ibase + ((lane >> 4) << 2));
#pragma unroll
      for (int r = 0; r < 4; ++r) {
        float wv = (r == 0) ? aw.x : (r == 1) ? aw.y : (r == 2) ? aw.z : aw.w;
#pragma unroll
        for (int nt = 0; nt < 4; ++nt)
          part[nt] += wv * fast_tanh(acc[nt][r] + b2v[nt]);
      }
    }
#pragma unroll
    for (int nt = 0; nt < 4; ++nt) {
      part[nt] += __shfl_xor(part[nt], 16);
      part[nt] += __shfl_xor(part[nt], 32);
    }
    if (lane < 16) {
#pragma unroll
      for (int nt = 0; nt < 4; ++nt) sh_aggw[wave][nt * 16 + lane] = part[nt];
    }
    __syncthreads();
    if (tid < 64)
      sh_agg[tid] = sh_aggw[0][tid] + sh_aggw[1][tid] + sh_aggw[2][tid] + sh_aggw[3][tid];
    __syncthreads();

    // ---- phase 3a: 4-wave parallel gate matvecs ----
    {
      const int h = lane;
      float s = my_bias;
      if (wave == 3) {
#pragma unroll
        for (int d = 0; d < 16; ++d) s += sh_x[d] * b2f(bw[BWIN + d * 64 + h]);
      } else {
        if (wave < 2) {
          const int xoff = (wave == 0) ? BWIR : BWII;
#pragma unroll
          for (int d = 0; d < 16; ++d) s += sh_x[d] * b2f(bw[xoff + d * 64 + h]);
        }
        const int woff = wave * 4096;  // HR@0 HI@4096 HH@8192
        for (int k = 0; k < 64; ++k) s += sh_agg[k] * b2f(lds_gate[woff + k * 64 + h]);
      }
      sh_pre[wave][h] = s;
    }
    __syncthreads();
    if (tid < 64) {
      float r  = fast_sigmoid(sh_pre[0][tid]);
      float ig = fast_sigmoid(sh_pre[1][tid]);
      float n  = fast_tanh(sh_pre[3][tid] + r * sh_pre[2][tid]);
      float hnew = (1.0f - ig) * n + ig * sh_hid[tid];
      sh_hid[tid] = hnew;
      ws[OFF_HIST + ((t * NBLK + bj) << 6) + tid] = hnew;  // for deferred output MLP
    }
    __syncthreads();

    // ---- phase 3b: next hs/hr over all 256 threads ----
    {
      const int m = tid & 127;
      const int isr = tid >> 7;  // 0: hs, 1: hr
      float s = isr ? my_bmsg1 : 0.0f;
      const int base = isr * 8192;
      for (int h = 0; h < 64; ++h) s += sh_hid[h] * b2f(lds_w1[base + h * 128 + m]);
      float* dst = isr ? hr_nxt : hs_nxt;
      dst[(bj << 7) + m] = s;
    }

    if (t < 14) grid_barrier(bar_count, bar_gen, t + 1);
  }
}

// ---------------- deferred output MLP + pred + mse partials ----------------
__launch_bounds__(256)
__global__ void out_kernel(const float* __restrict__ X,
                           const float* __restrict__ b_o1, const float* __restrict__ b_o2,
                           const float* __restrict__ b_o3,
                           float* __restrict__ ws, float* __restrict__ out) {
  const int tid = threadIdx.x, bj = blockIdx.x, b = bj >> 7, j = bj & 127;
  const int wave = tid >> 6, lane = tid & 63;
  const unsigned short* bw = (const unsigned short*)(ws + OFF_BF);
  const float* hist = ws + OFF_HIST;
  __shared__ float sh_h[4][64], sh_p[4][64], sh_q[4][64];
  __shared__ float sh_red[4];
  float bo1 = b_o1[lane], bo2 = b_o2[lane];
  float bo3 = (lane < 16) ? b_o3[lane] : 0.0f;
  float acc = 0.0f;
  for (int it = 0; it < 4; ++it) {
    const int tt = wave + it * 4;
    if (tt >= 15) break;  // wave-uniform
    sh_h[wave][lane] = hist[((tt * NBLK + bj) << 6) + lane];
    float s = bo1;
    for (int k = 0; k < 64; ++k) s += sh_h[wave][k] * b2f(bw[BWO1 + k * 64 + lane]);
    sh_p[wave][lane] = fmaxf(s, 0.0f);
    s = bo2;
    for (int k = 0; k < 64; ++k) s += sh_p[wave][k] * b2f(bw[BWO2 + k * 64 + lane]);
    sh_q[wave][lane] = fmaxf(s, 0.0f);
    if (lane < 16) {
      float s3 = bo3;
      for (int k = 0; k < 64; ++k) s3 += sh_q[wave][k] * b2f(bw[BWO3 + (k << 4) + lane]);
      const int xoff = (((b << 4) + tt) << 11) + (j << 4) + lane;
      float xt = X[xoff];
      float pred = xt + s3;
      out[((b * 15 + tt) * 128 + j) * 16 + lane] = pred;
      float d = X[xoff + 2048] - pred;  // next t
      acc += d * d;
    }
  }
  acc += __shfl_xor(acc, 1);
  acc += __shfl_xor(acc, 2);
  acc += __shfl_xor(acc, 4);
  acc += __shfl_xor(acc, 8);
  if (lane == 0) sh_red[wave] = acc;
  __syncthreads();
  if (tid == 0) ws[OFF_PART + bj] = sh_red[0] + sh_red[1] + sh_red[2] + sh_red[3];
}

// ---------------- finalize: loglik ----------------
__global__ void final_kernel(const float* __restrict__ log_sigma, const float* __restrict__ ws,
                             float* __restrict__ out) {
  __shared__ float red[256];
  const int tid = threadIdx.x;
  red[tid] = ws[OFF_PART + tid] + ws[OFF_PART + 256 + tid];
  __syncthreads();
  if (tid == 0) {
    float mse = 0.0f;
    for (int i = 0; i < 256; ++i) mse += red[i];
    float sigma = expf(log_sigma[0]);
    float cst = 8192.0f * logf(sigma * sqrtf(6.2831853071795864f));  // N*D*B
    out[122880] = -(mse / (2.0f * sigma * sigma) + 15.0f * cst);
  }
}

extern "C" void kernel_launch(void* const* d_in, const int* in_sizes, int n_in,
                              void* d_out, int out_size, void* d_ws, size_t ws_size,
                              hipStream_t stream) {
  (void)in_sizes; (void)n_in; (void)out_size; (void)ws_size;
  const float* A      = (const float*)d_in[0];
  const float* X      = (const float*)d_in[1];
  const float* W_msg1 = (const float*)d_in[2];
  const float* b_msg1 = (const float*)d_in[3];
  const float* W_msg2 = (const float*)d_in[4];
  const float* b_msg2 = (const float*)d_in[5];
  const float* W_ir   = (const float*)d_in[6];
  const float* b_ir   = (const float*)d_in[7];
  const float* W_ii   = (const float*)d_in[8];
  const float* b_ii   = (const float*)d_in[9];
  const float* W_in   = (const float*)d_in[10];
  const float* b_in   = (const float*)d_in[11];
  const float* W_hr   = (const float*)d_in[12];
  const float* W_hi   = (const float*)d_in[13];
  const float* W_hh   = (const float*)d_in[14];
  const float* W_o1   = (const float*)d_in[15];
  const float* b_o1   = (const float*)d_in[16];
  const float* W_o2   = (const float*)d_in[17];
  const float* b_o2   = (const float*)d_in[18];
  const float* W_o3   = (const float*)d_in[19];
  const float* b_o3   = (const float*)d_in[20];
  const float* log_sigma = (const float*)d_in[21];
  float* ws  = (float*)d_ws;
  float* out = (float*)d_out;

  init_kernel<<<(INIT_TOTAL + 255) / 256, 256, 0, stream>>>(
      A, b_msg1, W_msg2, W_ir, W_ii, W_in, W_hr, W_hi, W_hh, W_o1, W_o2, W_o3, W_msg1, ws);
  step_all_kernel<<<NBLK, 256, 0, stream>>>(X, b_msg1, b_msg2, b_ir, b_ii, b_in, ws);
  out_kernel<<<NBLK, 256, 0, stream>>>(X, b_o1, b_o2, b_o3, ws, out);
  final_kernel<<<1, 256, 0, stream>>>(log_sigma, ws, out);
}

// Round 3
// 561.521 us; speedup vs baseline: 1.6636x; 1.6636x over previous
//
#include <hip/hip_runtime.h>

// Dims: B=4, T=16, N=128, D=16, H=64, MH=128, 15 steps. NBLK=512 persistent blocks.
#define NBLK 512

// ---- workspace float offsets ----
#define OFF_A    0         // A_sym: 65536
#define OFF_HS   65536     // hs ping-pong: 2*65536
#define OFF_HIST 196608    // hidden history: 15*512*64 = 491520
#define OFF_PART 688128    // 512 mse partials
#define OFF_BAR  688640    // 32 ints (bar[t] arrival counters)
#define OFF_BF   688672    // bf16 weights: 49152 ushorts

// ---- bf16 (ushort) offsets within bf area ----
#define BW2F 0        // W_msg2 B-frags: 16*64*8 = 8192
#define BWIR 8192
#define BWII 9216
#define BWIN 10240
#define BWHR 11264
#define BWHI 15360
#define BWHH 19456
#define BWO1 23552
#define BWO2 27648
#define BWO3 31744
#define BW1S 32768    // W1s | W1r : 16384

#define INIT_TOTAL 180256

typedef __attribute__((ext_vector_type(8))) __bf16 bf16x8;
typedef __attribute__((ext_vector_type(4))) float f32x4;
union frag_u { bf16x8 v; unsigned short s[8]; int4 q; };

__device__ __forceinline__ unsigned short f2b(float x) {
  unsigned int u = __float_as_uint(x);
  u += 0x7fffu + ((u >> 16) & 1u);
  return (unsigned short)(u >> 16);
}
__device__ __forceinline__ float b2f(unsigned short u) {
  return __uint_as_float(((unsigned int)u) << 16);
}
__device__ __forceinline__ float fast_tanh(float x) {
  float e = __builtin_amdgcn_exp2f(x * 2.8853900817779268f);
  return 1.0f - 2.0f * __builtin_amdgcn_rcpf(e + 1.0f);
}
__device__ __forceinline__ float fast_sigmoid(float x) {
  float e = __builtin_amdgcn_exp2f(x * -1.4426950408889634f);
  return __builtin_amdgcn_rcpf(1.0f + e);
}

// coherent (agent-scope, write-through) store of one float — no cache walks
__device__ __forceinline__ void st_coh(float* p, float v) {
  __hip_atomic_store(p, v, __ATOMIC_RELAXED, __HIP_MEMORY_SCOPE_AGENT);
}

// ---------------- init ----------------
__global__ void init_kernel(const float* __restrict__ A, const float* __restrict__ W_msg2,
                            const float* __restrict__ W_ir, const float* __restrict__ W_ii,
                            const float* __restrict__ W_in,
                            const float* __restrict__ W_hr, const float* __restrict__ W_hi,
                            const float* __restrict__ W_hh,
                            const float* __restrict__ W_o1, const float* __restrict__ W_o2,
                            const float* __restrict__ W_o3,
                            const float* __restrict__ W_msg1, float* __restrict__ ws) {
  int idx = blockIdx.x * 256 + threadIdx.x;
  unsigned short* bw = (unsigned short*)(ws + OFF_BF);
  if (idx < 65536) {  // A_sym = clip(sym(A)*(1-I),0,1)
    int b = idx >> 14, rem = idx & 16383, i = rem >> 7, jj = rem & 127;
    float a  = A[idx];
    float at = A[(b << 14) + (jj << 7) + i];
    float v = 0.5f * (a + at);
    v = (i == jj) ? 0.0f : v;
    ws[OFF_A + idx] = fminf(fmaxf(v, 0.0f), 1.0f);
    return;
  }
  idx -= 65536;
  if (idx < 65536) { ws[OFF_HS + idx] = 0.0f; return; }   // hs parity-0 = 0
  idx -= 65536;
  if (idx < 32) { ((int*)(ws + OFF_BAR))[idx] = 0; return; }
  idx -= 32;
  if (idx < 8192) {  // W_msg2 B-frags
    int f = idx >> 9, l = (idx >> 3) & 63, jj = idx & 7;
    int kc = f >> 2, nt = f & 3;
    int k = kc * 32 + ((l >> 4) << 3) + jj;
    int n = (nt << 4) + (l & 15);
    bw[BW2F + idx] = f2b(W_msg2[k * 64 + n]);
    return;
  }
  idx -= 8192;
  if (idx < 1024) { bw[BWIR + idx] = f2b(W_ir[idx]); return; }
  idx -= 1024;
  if (idx < 1024) { bw[BWII + idx] = f2b(W_ii[idx]); return; }
  idx -= 1024;
  if (idx < 1024) { bw[BWIN + idx] = f2b(W_in[idx]); return; }
  idx -= 1024;
  if (idx < 4096) { bw[BWHR + idx] = f2b(W_hr[idx]); return; }
  idx -= 4096;
  if (idx < 4096) { bw[BWHI + idx] = f2b(W_hi[idx]); return; }
  idx -= 4096;
  if (idx < 4096) { bw[BWHH + idx] = f2b(W_hh[idx]); return; }
  idx -= 4096;
  if (idx < 4096) { bw[BWO1 + idx] = f2b(W_o1[idx]); return; }
  idx -= 4096;
  if (idx < 4096) { bw[BWO2 + idx] = f2b(W_o2[idx]); return; }
  idx -= 4096;
  if (idx < 1024) { bw[BWO3 + idx] = f2b(W_o3[idx]); return; }
  idx -= 1024;
  if (idx < 16384) { bw[BW1S + idx] = f2b(W_msg1[idx]); return; }
}

// ---------------- persistent: all 15 steps ----------------
__launch_bounds__(256, 2)
__global__ void step_all_kernel(const float* __restrict__ X,
                                const float* __restrict__ b_msg1, const float* __restrict__ b_msg2,
                                const float* __restrict__ b_ir, const float* __restrict__ b_ii,
                                const float* __restrict__ b_in,
                                float* __restrict__ ws) {
  const int tid = threadIdx.x;
  const int bj = blockIdx.x;
  const int b = bj >> 7, j = bj & 127;
  const int wave = tid >> 6, lane = tid & 63;
  const unsigned short* bw = (const unsigned short*)(ws + OFF_BF);
  int* bar = (int*)(ws + OFF_BAR);

  __shared__ unsigned short lds_gate[12288];  // W_hr@0 | W_hi@4096 | W_hh@8192
  __shared__ unsigned short lds_w1[16384];    // W1s@0 | W1r@8192
  __shared__ __align__(16) float sh_hr[128];  // hr row j — block-private, lives in LDS
  __shared__ __align__(16) float sh_Ar[128];
  __shared__ float sh_aggw[4][64];
  __shared__ float sh_agg[64];
  __shared__ float sh_x[16];
  __shared__ float sh_hid[64];
  __shared__ float sh_pre[4][64];  // pre_r | pre_i | hh | pre_nx

  // ---- one-time staging ----
  {
    const int4* src = (const int4*)(bw + BWHR);   // 12288 ushorts = 1536 int4
    int4* dst = (int4*)lds_gate;
    for (int i = tid; i < 1536; i += 256) dst[i] = src[i];
    const int4* s2 = (const int4*)(bw + BW1S);    // 16384 ushorts = 2048 int4
    int4* d2 = (int4*)lds_w1;
    for (int i = tid; i < 2048; i += 256) d2[i] = s2[i];
  }
  if (tid < 128) {
    sh_Ar[tid] = ws[OFF_A + (b << 14) + (j << 7) + tid];  // A_sym symmetric: row j == col j
    sh_hr[tid] = b_msg1[tid];                             // hr_0 = hidden0@W1r + b = b_msg1
  } else if (tid < 192) {
    sh_hid[tid - 128] = 0.0f;
  }

  // persistent register state
  frag_u Bf[16];
  const int4* bw2 = (const int4*)bw;  // BW2F == 0
#pragma unroll
  for (int f = 0; f < 16; ++f) Bf[f].q = bw2[f * 64 + lane];
  float b2v[4];
#pragma unroll
  for (int nt = 0; nt < 4; ++nt) b2v[nt] = b_msg2[nt * 16 + (lane & 15)];
  float my_bias = 0.0f;
  if (wave == 0) my_bias = b_ir[lane];
  else if (wave == 1) my_bias = b_ii[lane];
  else if (wave == 3) my_bias = b_in[lane];
  float my_bmsg1 = (tid >= 128) ? b_msg1[tid - 128] : 0.0f;

  const int lane15 = lane & 15;
  const int k0 = (lane >> 4) << 3;
  __syncthreads();

  for (int t = 0; t < 15; ++t) {
    const int par = t & 1;
    const float* hs_cur = ws + OFF_HS + par * 65536;
    float* hs_nxt = ws + OFF_HS + (par ^ 1) * 65536;

    if (tid < 16) sh_x[tid] = X[(((b << 4) + t) << 11) + (j << 4) + tid];

    // ---- phase 2: batch-prefetch my 64 hs floats via coherent (sc0 sc1) loads ----
    float4 va[2][8];
    {
      const float* p0 = hs_cur + (((b << 7) + (wave << 5) + lane15) << 7) + k0;  // c=0 row
      const float* p1 = p0 + 2048;                                               // c=1: +16 rows
      asm volatile(
          "global_load_dwordx4 %0, %16, off sc0 sc1\n\t"
          "global_load_dwordx4 %1, %16, off offset:16 sc0 sc1\n\t"
          "global_load_dwordx4 %2, %16, off offset:128 sc0 sc1\n\t"
          "global_load_dwordx4 %3, %16, off offset:144 sc0 sc1\n\t"
          "global_load_dwordx4 %4, %16, off offset:256 sc0 sc1\n\t"
          "global_load_dwordx4 %5, %16, off offset:272 sc0 sc1\n\t"
          "global_load_dwordx4 %6, %16, off offset:384 sc0 sc1\n\t"
          "global_load_dwordx4 %7, %16, off offset:400 sc0 sc1\n\t"
          "global_load_dwordx4 %8, %17, off sc0 sc1\n\t"
          "global_load_dwordx4 %9, %17, off offset:16 sc0 sc1\n\t"
          "global_load_dwordx4 %10, %17, off offset:128 sc0 sc1\n\t"
          "global_load_dwordx4 %11, %17, off offset:144 sc0 sc1\n\t"
          "global_load_dwordx4 %12, %17, off offset:256 sc0 sc1\n\t"
          "global_load_dwordx4 %13, %17, off offset:272 sc0 sc1\n\t"
          "global_load_dwordx4 %14, %17, off offset:384 sc0 sc1\n\t"
          "global_load_dwordx4 %15, %17, off offset:400 sc0 sc1\n\t"
          "s_waitcnt vmcnt(0)"
          : "=&v"(va[0][0]), "=&v"(va[0][1]), "=&v"(va[0][2]), "=&v"(va[0][3]),
            "=&v"(va[0][4]), "=&v"(va[0][5]), "=&v"(va[0][6]), "=&v"(va[0][7]),
            "=&v"(va[1][0]), "=&v"(va[1][1]), "=&v"(va[1][2]), "=&v"(va[1][3]),
            "=&v"(va[1][4]), "=&v"(va[1][5]), "=&v"(va[1][6]), "=&v"(va[1][7])
          : "v"(p0), "v"(p1)
          : "memory");
    }

    float part[4] = {0.f, 0.f, 0.f, 0.f};
#pragma unroll
    for (int c = 0; c < 2; ++c) {
      f32x4 acc[4];
#pragma unroll
      for (int nt = 0; nt < 4; ++nt) acc[nt] = (f32x4){0.f, 0.f, 0.f, 0.f};
#pragma unroll
      for (int kc = 0; kc < 4; ++kc) {
        const float4 a0 = va[c][kc * 2];
        const float4 a1 = va[c][kc * 2 + 1];
        const float* hp = sh_hr + kc * 32 + k0;
        frag_u Af;
        Af.s[0] = f2b(fast_tanh(a0.x + hp[0]));
        Af.s[1] = f2b(fast_tanh(a0.y + hp[1]));
        Af.s[2] = f2b(fast_tanh(a0.z + hp[2]));
        Af.s[3] = f2b(fast_tanh(a0.w + hp[3]));
        Af.s[4] = f2b(fast_tanh(a1.x + hp[4]));
        Af.s[5] = f2b(fast_tanh(a1.y + hp[5]));
        Af.s[6] = f2b(fast_tanh(a1.z + hp[6]));
        Af.s[7] = f2b(fast_tanh(a1.w + hp[7]));
#pragma unroll
        for (int nt = 0; nt < 4; ++nt)
          acc[nt] = __builtin_amdgcn_mfma_f32_16x16x32_bf16(Af.v, Bf[kc * 4 + nt].v, acc[nt], 0, 0, 0);
      }
      const int ibase = ((wave << 1) + c) << 4;
      float4 aw = *(const float4*)(sh_Ar + ibase + ((lane >> 4) << 2));
#pragma unroll
      for (int r = 0; r < 4; ++r) {
        float wv = (r == 0) ? aw.x : (r == 1) ? aw.y : (r == 2) ? aw.z : aw.w;
#pragma unroll
        for (int nt = 0; nt < 4; ++nt)
          part[nt] += wv * fast_tanh(acc[nt][r] + b2v[nt]);
      }
    }
#pragma unroll
    for (int nt = 0; nt < 4; ++nt) {
      part[nt] += __shfl_xor(part[nt], 16);
      part[nt] += __shfl_xor(part[nt], 32);
    }
    if (lane < 16) {
#pragma unroll
      for (int nt = 0; nt < 4; ++nt) sh_aggw[wave][nt * 16 + lane] = part[nt];
    }
    __syncthreads();
    if (tid < 64)
      sh_agg[tid] = sh_aggw[0][tid] + sh_aggw[1][tid] + sh_aggw[2][tid] + sh_aggw[3][tid];
    __syncthreads();

    // ---- phase 3a: 4-wave parallel gate matvecs ----
    {
      const int h = lane;
      float s = my_bias;
      if (wave == 3) {
#pragma unroll
        for (int d = 0; d < 16; ++d) s += sh_x[d] * b2f(bw[BWIN + d * 64 + h]);
      } else {
        if (wave < 2) {
          const int xoff = (wave == 0) ? BWIR : BWII;
#pragma unroll
          for (int d = 0; d < 16; ++d) s += sh_x[d] * b2f(bw[xoff + d * 64 + h]);
        }
        const int woff = wave * 4096;  // HR@0 HI@4096 HH@8192
        for (int k = 0; k < 64; ++k) s += sh_agg[k] * b2f(lds_gate[woff + k * 64 + h]);
      }
      sh_pre[wave][h] = s;
    }
    __syncthreads();
    if (tid < 64) {
      float r  = fast_sigmoid(sh_pre[0][tid]);
      float ig = fast_sigmoid(sh_pre[1][tid]);
      float n  = fast_tanh(sh_pre[3][tid] + r * sh_pre[2][tid]);
      float hnew = (1.0f - ig) * n + ig * sh_hid[tid];
      sh_hid[tid] = hnew;
      ws[OFF_HIST + ((t * NBLK + bj) << 6) + tid] = hnew;  // plain store; read next dispatch
    }
    __syncthreads();

    if (t < 14) {
      // ---- phase 3b: next hs (coherent, cross-block) / next hr (LDS, private) ----
      {
        const int m = tid & 127;
        const int isr = tid >> 7;  // 0: hs, 1: hr
        float s = isr ? my_bmsg1 : 0.0f;
        const int base = isr * 8192;
        for (int h = 0; h < 64; ++h) s += sh_hid[h] * b2f(lds_w1[base + h * 128 + m]);
        if (isr) sh_hr[m] = s;                 // block-private
        else st_coh(&hs_nxt[(bj << 7) + m], s);  // write-through to coherent point
      }
      // ---- fence-free grid barrier ----
      asm volatile("s_waitcnt vmcnt(0)" ::: "memory");  // my wave's sc1 stores acked
      __syncthreads();                                   // all waves' stores acked
      if (tid == 0) {
        int* cnt = bar + t;
        __hip_atomic_fetch_add(cnt, 1, __ATOMIC_RELAXED, __HIP_MEMORY_SCOPE_AGENT);
        while (__hip_atomic_load(cnt, __ATOMIC_RELAXED, __HIP_MEMORY_SCOPE_AGENT) < NBLK)
          __builtin_amdgcn_s_sleep(8);
      }
      __syncthreads();
    }
  }
}

// ---------------- deferred output MLP + pred + mse partials ----------------
__launch_bounds__(256)
__global__ void out_kernel(const float* __restrict__ X,
                           const float* __restrict__ b_o1, const float* __restrict__ b_o2,
                           const float* __restrict__ b_o3,
                           float* __restrict__ ws, float* __restrict__ out) {
  const int tid = threadIdx.x, bj = blockIdx.x, b = bj >> 7, j = bj & 127;
  const int wave = tid >> 6, lane = tid & 63;
  const unsigned short* bw = (const unsigned short*)(ws + OFF_BF);
  const float* hist = ws + OFF_HIST;
  __shared__ float sh_h[4][64], sh_p[4][64], sh_q[4][64];
  __shared__ float sh_red[4];
  float bo1 = b_o1[lane], bo2 = b_o2[lane];
  float bo3 = (lane < 16) ? b_o3[lane] : 0.0f;
  float acc = 0.0f;
  for (int it = 0; it < 4; ++it) {
    const int tt = wave + it * 4;
    if (tt >= 15) break;  // wave-uniform
    sh_h[wave][lane] = hist[((tt * NBLK + bj) << 6) + lane];
    float s = bo1;
    for (int k = 0; k < 64; ++k) s += sh_h[wave][k] * b2f(bw[BWO1 + k * 64 + lane]);
    sh_p[wave][lane] = fmaxf(s, 0.0f);
    s = bo2;
    for (int k = 0; k < 64; ++k) s += sh_p[wave][k] * b2f(bw[BWO2 + k * 64 + lane]);
    sh_q[wave][lane] = fmaxf(s, 0.0f);
    if (lane < 16) {
      float s3 = bo3;
      for (int k = 0; k < 64; ++k) s3 += sh_q[wave][k] * b2f(bw[BWO3 + (k << 4) + lane]);
      const int xoff = (((b << 4) + tt) << 11) + (j << 4) + lane;
      float xt = X[xoff];
      float pred = xt + s3;
      out[((b * 15 + tt) * 128 + j) * 16 + lane] = pred;
      float d = X[xoff + 2048] - pred;  // next t
      acc += d * d;
    }
  }
  acc += __shfl_xor(acc, 1);
  acc += __shfl_xor(acc, 2);
  acc += __shfl_xor(acc, 4);
  acc += __shfl_xor(acc, 8);
  if (lane == 0) sh_red[wave] = acc;
  __syncthreads();
  if (tid == 0) ws[OFF_PART + bj] = sh_red[0] + sh_red[1] + sh_red[2] + sh_red[3];
}

// ---------------- finalize: loglik ----------------
__global__ void final_kernel(const float* __restrict__ log_sigma, const float* __restrict__ ws,
                             float* __restrict__ out) {
  __shared__ float red[256];
  const int tid = threadIdx.x;
  red[tid] = ws[OFF_PART + tid] + ws[OFF_PART + 256 + tid];
  __syncthreads();
  if (tid == 0) {
    float mse = 0.0f;
    for (int i = 0; i < 256; ++i) mse += red[i];
    float sigma = expf(log_sigma[0]);
    float cst = 8192.0f * logf(sigma * sqrtf(6.2831853071795864f));  // N*D*B
    out[122880] = -(mse / (2.0f * sigma * sigma) + 15.0f * cst);
  }
}

extern "C" void kernel_launch(void* const* d_in, const int* in_sizes, int n_in,
                              void* d_out, int out_size, void* d_ws, size_t ws_size,
                              hipStream_t stream) {
  (void)in_sizes; (void)n_in; (void)out_size; (void)ws_size;
  const float* A      = (const float*)d_in[0];
  const float* X      = (const float*)d_in[1];
  const float* W_msg1 = (const float*)d_in[2];
  const float* b_msg1 = (const float*)d_in[3];
  const float* W_msg2 = (const float*)d_in[4];
  const float* b_msg2 = (const float*)d_in[5];
  const float* W_ir   = (const float*)d_in[6];
  const float* b_ir   = (const float*)d_in[7];
  const float* W_ii   = (const float*)d_in[8];
  const float* b_ii   = (const float*)d_in[9];
  const float* W_in   = (const float*)d_in[10];
  const float* b_in   = (const float*)d_in[11];
  const float* W_hr   = (const float*)d_in[12];
  const float* W_hi   = (const float*)d_in[13];
  const float* W_hh   = (const float*)d_in[14];
  const float* W_o1   = (const float*)d_in[15];
  const float* b_o1   = (const float*)d_in[16];
  const float* W_o2   = (const float*)d_in[17];
  const float* b_o2   = (const float*)d_in[18];
  const float* W_o3   = (const float*)d_in[19];
  const float* b_o3   = (const float*)d_in[20];
  const float* log_sigma = (const float*)d_in[21];
  float* ws  = (float*)d_ws;
  float* out = (float*)d_out;

  init_kernel<<<(INIT_TOTAL + 255) / 256, 256, 0, stream>>>(
      A, W_msg2, W_ir, W_ii, W_in, W_hr, W_hi, W_hh, W_o1, W_o2, W_o3, W_msg1, ws);
  step_all_kernel<<<NBLK, 256, 0, stream>>>(X, b_msg1, b_msg2, b_ir, b_ii, b_in, ws);
  out_kernel<<<NBLK, 256, 0, stream>>>(X, b_o1, b_o2, b_o3, ws, out);
  final_kernel<<<1, 256, 0, stream>>>(log_sigma, ws, out);
}

// Round 4
// 357.443 us; speedup vs baseline: 2.6134x; 1.5709x over previous
//
#include <hip/hip_runtime.h>

// Dims: B=4, T=16, N=128, D=16, H=64, MH=128, 15 steps. NBLK=512 persistent blocks.
#define NBLK 512

// ---- workspace float offsets ----
#define OFF_A    0         // A_sym: 65536
#define OFF_HS   65536     // hs ping-pong: 2*65536
#define OFF_HIST 196608    // hidden history: 15*512*64 = 491520
#define OFF_PART 688128    // 512 mse partials
#define OFF_SYNC 688640    // 19200 ints: leaf[4*15*8]x32 | root[60]x32 | flag[60]x32
#define OFF_BF   707840    // bf16 weights: 49152 ushorts

// sync sub-offsets (ints, each slot stride 32 = 128B line)
#define SYNC_ROOT 15360
#define SYNC_FLAG 17280

// ---- bf16 (ushort) offsets within bf area ----
#define BW2F 0        // W_msg2 B-frags: 16*64*8 = 8192
#define BWIR 8192
#define BWII 9216
#define BWIN 10240
#define BWHR 11264
#define BWHI 15360
#define BWHH 19456
#define BWO1 23552
#define BWO2 27648
#define BWO3 31744
#define BW1S 32768    // W1s | W1r : 16384

#define INIT_TOTAL 199424

typedef __attribute__((ext_vector_type(8))) __bf16 bf16x8;
typedef __attribute__((ext_vector_type(4))) float f32x4;
union frag_u { bf16x8 v; unsigned short s[8]; int4 q; };

__device__ __forceinline__ unsigned short f2b(float x) {
  unsigned int u = __float_as_uint(x);
  u += 0x7fffu + ((u >> 16) & 1u);
  return (unsigned short)(u >> 16);
}
__device__ __forceinline__ float b2f(unsigned short u) {
  return __uint_as_float(((unsigned int)u) << 16);
}
__device__ __forceinline__ float fast_tanh(float x) {
  float e = __builtin_amdgcn_exp2f(x * 2.8853900817779268f);
  return 1.0f - 2.0f * __builtin_amdgcn_rcpf(e + 1.0f);
}
__device__ __forceinline__ float fast_sigmoid(float x) {
  float e = __builtin_amdgcn_exp2f(x * -1.4426950408889634f);
  return __builtin_amdgcn_rcpf(1.0f + e);
}

// coherent (agent-scope, write-through) store of one float — no cache walks
__device__ __forceinline__ void st_coh(float* p, float v) {
  __hip_atomic_store(p, v, __ATOMIC_RELAXED, __HIP_MEMORY_SCOPE_AGENT);
}

// ---------------- init ----------------
__global__ void init_kernel(const float* __restrict__ A, const float* __restrict__ W_msg2,
                            const float* __restrict__ W_ir, const float* __restrict__ W_ii,
                            const float* __restrict__ W_in,
                            const float* __restrict__ W_hr, const float* __restrict__ W_hi,
                            const float* __restrict__ W_hh,
                            const float* __restrict__ W_o1, const float* __restrict__ W_o2,
                            const float* __restrict__ W_o3,
                            const float* __restrict__ W_msg1, float* __restrict__ ws) {
  int idx = blockIdx.x * 256 + threadIdx.x;
  unsigned short* bw = (unsigned short*)(ws + OFF_BF);
  if (idx < 65536) {  // A_sym = clip(sym(A)*(1-I),0,1)
    int b = idx >> 14, rem = idx & 16383, i = rem >> 7, jj = rem & 127;
    float a  = A[idx];
    float at = A[(b << 14) + (jj << 7) + i];
    float v = 0.5f * (a + at);
    v = (i == jj) ? 0.0f : v;
    ws[OFF_A + idx] = fminf(fmaxf(v, 0.0f), 1.0f);
    return;
  }
  idx -= 65536;
  if (idx < 65536) { ws[OFF_HS + idx] = 0.0f; return; }   // hs parity-0 = 0
  idx -= 65536;
  if (idx < 19200) { ((int*)(ws + OFF_SYNC))[idx] = 0; return; }  // barrier slots
  idx -= 19200;
  if (idx < 8192) {  // W_msg2 B-frags
    int f = idx >> 9, l = (idx >> 3) & 63, jj = idx & 7;
    int kc = f >> 2, nt = f & 3;
    int k = kc * 32 + ((l >> 4) << 3) + jj;
    int n = (nt << 4) + (l & 15);
    bw[BW2F + idx] = f2b(W_msg2[k * 64 + n]);
    return;
  }
  idx -= 8192;
  if (idx < 1024) { bw[BWIR + idx] = f2b(W_ir[idx]); return; }
  idx -= 1024;
  if (idx < 1024) { bw[BWII + idx] = f2b(W_ii[idx]); return; }
  idx -= 1024;
  if (idx < 1024) { bw[BWIN + idx] = f2b(W_in[idx]); return; }
  idx -= 1024;
  if (idx < 4096) { bw[BWHR + idx] = f2b(W_hr[idx]); return; }
  idx -= 4096;
  if (idx < 4096) { bw[BWHI + idx] = f2b(W_hi[idx]); return; }
  idx -= 4096;
  if (idx < 4096) { bw[BWHH + idx] = f2b(W_hh[idx]); return; }
  idx -= 4096;
  if (idx < 4096) { bw[BWO1 + idx] = f2b(W_o1[idx]); return; }
  idx -= 4096;
  if (idx < 4096) { bw[BWO2 + idx] = f2b(W_o2[idx]); return; }
  idx -= 4096;
  if (idx < 1024) { bw[BWO3 + idx] = f2b(W_o3[idx]); return; }
  idx -= 1024;
  if (idx < 16384) { bw[BW1S + idx] = f2b(W_msg1[idx]); return; }
}

// ---------------- persistent: all 15 steps ----------------
__launch_bounds__(256, 2)
__global__ void step_all_kernel(const float* __restrict__ X,
                                const float* __restrict__ b_msg1, const float* __restrict__ b_msg2,
                                const float* __restrict__ b_ir, const float* __restrict__ b_ii,
                                const float* __restrict__ b_in,
                                float* __restrict__ ws) {
  const int tid = threadIdx.x;
  const int bj = blockIdx.x;
  const int b = bj >> 7, j = bj & 127;
  const int wave = tid >> 6, lane = tid & 63;
  const unsigned short* bw = (const unsigned short*)(ws + OFF_BF);
  int* sync = (int*)(ws + OFF_SYNC);

  __shared__ unsigned short lds_gate[12288];  // W_hr@0 | W_hi@4096 | W_hh@8192
  __shared__ unsigned short lds_w1[16384];    // W1s@0 | W1r@8192
  __shared__ __align__(16) float sh_hr[128];  // hr row j — block-private
  __shared__ __align__(16) float sh_Ar[128];
  __shared__ float sh_aggw[4][64];
  __shared__ float sh_agg[64];
  __shared__ float sh_x[16];
  __shared__ float sh_hid[64];
  __shared__ float sh_pre[4][64];  // pre_r | pre_i | hh | pre_nx

  // ---- one-time staging ----
  {
    const int4* src = (const int4*)(bw + BWHR);   // 12288 ushorts = 1536 int4
    int4* dst = (int4*)lds_gate;
    for (int i = tid; i < 1536; i += 256) dst[i] = src[i];
    const int4* s2 = (const int4*)(bw + BW1S);    // 16384 ushorts = 2048 int4
    int4* d2 = (int4*)lds_w1;
    for (int i = tid; i < 2048; i += 256) d2[i] = s2[i];
  }
  if (tid < 128) {
    sh_Ar[tid] = ws[OFF_A + (b << 14) + (j << 7) + tid];  // A_sym symmetric: row j == col j
    sh_hr[tid] = b_msg1[tid];                             // hr_0 = b_msg1
  } else if (tid < 192) {
    sh_hid[tid - 128] = 0.0f;
  }

  // persistent register state
  frag_u Bf[16];
  const int4* bw2 = (const int4*)bw;  // BW2F == 0
#pragma unroll
  for (int f = 0; f < 16; ++f) Bf[f].q = bw2[f * 64 + lane];
  float b2v[4];
#pragma unroll
  for (int nt = 0; nt < 4; ++nt) b2v[nt] = b_msg2[nt * 16 + (lane & 15)];
  float my_bias = 0.0f;
  if (wave == 0) my_bias = b_ir[lane];
  else if (wave == 1) my_bias = b_ii[lane];
  else if (wave == 3) my_bias = b_in[lane];
  float my_bmsg1 = (tid >= 128) ? b_msg1[tid - 128] : 0.0f;

  const int lane15 = lane & 15;
  const int k0 = (lane >> 4) << 3;
  __syncthreads();

  for (int t = 0; t < 15; ++t) {
    const int par = t & 1;
    const float* hs_cur = ws + OFF_HS + par * 65536;
    float* hs_nxt = ws + OFF_HS + (par ^ 1) * 65536;

    if (tid < 16) sh_x[tid] = X[(((b << 4) + t) << 11) + (j << 4) + tid];

    // ---- phase 2: batch-prefetch my 64 hs floats via coherent (sc0 sc1) loads ----
    float4 va[2][8];
    {
      const float* p0 = hs_cur + (((b << 7) + (wave << 5) + lane15) << 7) + k0;  // c=0 row
      const float* p1 = p0 + 2048;                                               // c=1: +16 rows
      asm volatile(
          "global_load_dwordx4 %0, %16, off sc0 sc1\n\t"
          "global_load_dwordx4 %1, %16, off offset:16 sc0 sc1\n\t"
          "global_load_dwordx4 %2, %16, off offset:128 sc0 sc1\n\t"
          "global_load_dwordx4 %3, %16, off offset:144 sc0 sc1\n\t"
          "global_load_dwordx4 %4, %16, off offset:256 sc0 sc1\n\t"
          "global_load_dwordx4 %5, %16, off offset:272 sc0 sc1\n\t"
          "global_load_dwordx4 %6, %16, off offset:384 sc0 sc1\n\t"
          "global_load_dwordx4 %7, %16, off offset:400 sc0 sc1\n\t"
          "global_load_dwordx4 %8, %17, off sc0 sc1\n\t"
          "global_load_dwordx4 %9, %17, off offset:16 sc0 sc1\n\t"
          "global_load_dwordx4 %10, %17, off offset:128 sc0 sc1\n\t"
          "global_load_dwordx4 %11, %17, off offset:144 sc0 sc1\n\t"
          "global_load_dwordx4 %12, %17, off offset:256 sc0 sc1\n\t"
          "global_load_dwordx4 %13, %17, off offset:272 sc0 sc1\n\t"
          "global_load_dwordx4 %14, %17, off offset:384 sc0 sc1\n\t"
          "global_load_dwordx4 %15, %17, off offset:400 sc0 sc1\n\t"
          "s_waitcnt vmcnt(0)"
          : "=&v"(va[0][0]), "=&v"(va[0][1]), "=&v"(va[0][2]), "=&v"(va[0][3]),
            "=&v"(va[0][4]), "=&v"(va[0][5]), "=&v"(va[0][6]), "=&v"(va[0][7]),
            "=&v"(va[1][0]), "=&v"(va[1][1]), "=&v"(va[1][2]), "=&v"(va[1][3]),
            "=&v"(va[1][4]), "=&v"(va[1][5]), "=&v"(va[1][6]), "=&v"(va[1][7])
          : "v"(p0), "v"(p1)
          : "memory");
    }

    float part[4] = {0.f, 0.f, 0.f, 0.f};
#pragma unroll
    for (int c = 0; c < 2; ++c) {
      f32x4 acc[4];
#pragma unroll
      for (int nt = 0; nt < 4; ++nt) acc[nt] = (f32x4){0.f, 0.f, 0.f, 0.f};
#pragma unroll
      for (int kc = 0; kc < 4; ++kc) {
        const float4 a0 = va[c][kc * 2];
        const float4 a1 = va[c][kc * 2 + 1];
        const float* hp = sh_hr + kc * 32 + k0;
        frag_u Af;
        Af.s[0] = f2b(fast_tanh(a0.x + hp[0]));
        Af.s[1] = f2b(fast_tanh(a0.y + hp[1]));
        Af.s[2] = f2b(fast_tanh(a0.z + hp[2]));
        Af.s[3] = f2b(fast_tanh(a0.w + hp[3]));
        Af.s[4] = f2b(fast_tanh(a1.x + hp[4]));
        Af.s[5] = f2b(fast_tanh(a1.y + hp[5]));
        Af.s[6] = f2b(fast_tanh(a1.z + hp[6]));
        Af.s[7] = f2b(fast_tanh(a1.w + hp[7]));
#pragma unroll
        for (int nt = 0; nt < 4; ++nt)
          acc[nt] = __builtin_amdgcn_mfma_f32_16x16x32_bf16(Af.v, Bf[kc * 4 + nt].v, acc[nt], 0, 0, 0);
      }
      const int ibase = ((wave << 1) + c) << 4;
      float4 aw = *(const float4*)(sh_Ar + ibase + ((lane >> 4) << 2));
#pragma unroll
      for (int r = 0; r < 4; ++r) {
        float wv = (r == 0) ? aw.x : (r == 1) ? aw.y : (r == 2) ? aw.z : aw.w;
#pragma unroll
        for (int nt = 0; nt < 4; ++nt)
          part[nt] += wv * fast_tanh(acc[nt][r] + b2v[nt]);
      }
    }
#pragma unroll
    for (int nt = 0; nt < 4; ++nt) {
      part[nt] += __shfl_xor(part[nt], 16);
      part[nt] += __shfl_xor(part[nt], 32);
    }
    if (lane < 16) {
#pragma unroll
      for (int nt = 0; nt < 4; ++nt) sh_aggw[wave][nt * 16 + lane] = part[nt];
    }
    __syncthreads();
    if (tid < 64)
      sh_agg[tid] = sh_aggw[0][tid] + sh_aggw[1][tid] + sh_aggw[2][tid] + sh_aggw[3][tid];
    __syncthreads();

    // ---- phase 3a: 4-wave parallel gate matvecs ----
    {
      const int h = lane;
      float s = my_bias;
      if (wave == 3) {
#pragma unroll
        for (int d = 0; d < 16; ++d) s += sh_x[d] * b2f(bw[BWIN + d * 64 + h]);
      } else {
        if (wave < 2) {
          const int xoff = (wave == 0) ? BWIR : BWII;
#pragma unroll
          for (int d = 0; d < 16; ++d) s += sh_x[d] * b2f(bw[xoff + d * 64 + h]);
        }
        const int woff = wave * 4096;  // HR@0 HI@4096 HH@8192
        for (int k = 0; k < 64; ++k) s += sh_agg[k] * b2f(lds_gate[woff + k * 64 + h]);
      }
      sh_pre[wave][h] = s;
    }
    __syncthreads();
    if (tid < 64) {
      float r  = fast_sigmoid(sh_pre[0][tid]);
      float ig = fast_sigmoid(sh_pre[1][tid]);
      float n  = fast_tanh(sh_pre[3][tid] + r * sh_pre[2][tid]);
      float hnew = (1.0f - ig) * n + ig * sh_hid[tid];
      sh_hid[tid] = hnew;
      ws[OFF_HIST + ((t * NBLK + bj) << 6) + tid] = hnew;  // plain store; read next dispatch
    }
    __syncthreads();

    if (t < 14) {
      // ---- phase 3b: next hs (coherent, cross-block) / next hr (LDS, private) ----
      {
        const int m = tid & 127;
        const int isr = tid >> 7;  // 0: hs, 1: hr
        float s = isr ? my_bmsg1 : 0.0f;
        const int base = isr * 8192;
        for (int h = 0; h < 64; ++h) s += sh_hid[h] * b2f(lds_w1[base + h * 128 + m]);
        if (isr) sh_hr[m] = s;                    // block-private
        else st_coh(&hs_nxt[(bj << 7) + m], s);   // write-through to coherent point
      }
      // ---- per-batch 2-level barrier, split counters/flag lines ----
      asm volatile("s_waitcnt vmcnt(0)" ::: "memory");  // my wave's sc1 stores acked
      __syncthreads();                                   // all waves' stores acked
      if (tid == 0) {
        const int bt = b * 15 + t;
        int* leaf = sync + ((bt << 3) + (bj & 7)) * 32;   // 16 arrivals per leaf line
        int* root = sync + SYNC_ROOT + bt * 32;           // 8 arrivals
        int* flag = sync + SYNC_FLAG + bt * 32;           // read-only for pollers
        int r = __hip_atomic_fetch_add(leaf, 1, __ATOMIC_RELAXED, __HIP_MEMORY_SCOPE_AGENT);
        if (r == 15) {
          int r2 = __hip_atomic_fetch_add(root, 1, __ATOMIC_RELAXED, __HIP_MEMORY_SCOPE_AGENT);
          if (r2 == 7)
            __hip_atomic_store(flag, 1, __ATOMIC_RELAXED, __HIP_MEMORY_SCOPE_AGENT);
        }
        while (__hip_atomic_load(flag, __ATOMIC_RELAXED, __HIP_MEMORY_SCOPE_AGENT) == 0)
          __builtin_amdgcn_s_sleep(2);
      }
      __syncthreads();
    }
  }
}

// ---------------- deferred output MLP + pred + mse partials ----------------
__launch_bounds__(256)
__global__ void out_kernel(const float* __restrict__ X,
                           const float* __restrict__ b_o1, const float* __restrict__ b_o2,
                           const float* __restrict__ b_o3,
                           float* __restrict__ ws, float* __restrict__ out) {
  const int tid = threadIdx.x, bj = blockIdx.x, b = bj >> 7, j = bj & 127;
  const int wave = tid >> 6, lane = tid & 63;
  const unsigned short* bw = (const unsigned short*)(ws + OFF_BF);
  const float* hist = ws + OFF_HIST;
  __shared__ float sh_h[4][64], sh_p[4][64], sh_q[4][64];
  __shared__ float sh_red[4];
  float bo1 = b_o1[lane], bo2 = b_o2[lane];
  float bo3 = (lane < 16) ? b_o3[lane] : 0.0f;
  float acc = 0.0f;
  for (int it = 0; it < 4; ++it) {
    const int tt = wave + it * 4;
    if (tt >= 15) break;  // wave-uniform
    sh_h[wave][lane] = hist[((tt * NBLK + bj) << 6) + lane];
    float s = bo1;
    for (int k = 0; k < 64; ++k) s += sh_h[wave][k] * b2f(bw[BWO1 + k * 64 + lane]);
    sh_p[wave][lane] = fmaxf(s, 0.0f);
    s = bo2;
    for (int k = 0; k < 64; ++k) s += sh_p[wave][k] * b2f(bw[BWO2 + k * 64 + lane]);
    sh_q[wave][lane] = fmaxf(s, 0.0f);
    if (lane < 16) {
      float s3 = bo3;
      for (int k = 0; k < 64; ++k) s3 += sh_q[wave][k] * b2f(bw[BWO3 + (k << 4) + lane]);
      const int xoff = (((b << 4) + tt) << 11) + (j << 4) + lane;
      float xt = X[xoff];
      float pred = xt + s3;
      out[((b * 15 + tt) * 128 + j) * 16 + lane] = pred;
      float d = X[xoff + 2048] - pred;  // next t
      acc += d * d;
    }
  }
  acc += __shfl_xor(acc, 1);
  acc += __shfl_xor(acc, 2);
  acc += __shfl_xor(acc, 4);
  acc += __shfl_xor(acc, 8);
  if (lane == 0) sh_red[wave] = acc;
  __syncthreads();
  if (tid == 0) ws[OFF_PART + bj] = sh_red[0] + sh_red[1] + sh_red[2] + sh_red[3];
}

// ---------------- finalize: loglik ----------------
__global__ void final_kernel(const float* __restrict__ log_sigma, const float* __restrict__ ws,
                             float* __restrict__ out) {
  __shared__ float red[256];
  const int tid = threadIdx.x;
  red[tid] = ws[OFF_PART + tid] + ws[OFF_PART + 256 + tid];
  __syncthreads();
  if (tid == 0) {
    float mse = 0.0f;
    for (int i = 0; i < 256; ++i) mse += red[i];
    float sigma = expf(log_sigma[0]);
    float cst = 8192.0f * logf(sigma * sqrtf(6.2831853071795864f));  // N*D*B
    out[122880] = -(mse / (2.0f * sigma * sigma) + 15.0f * cst);
  }
}

extern "C" void kernel_launch(void* const* d_in, const int* in_sizes, int n_in,
                              void* d_out, int out_size, void* d_ws, size_t ws_size,
                              hipStream_t stream) {
  (void)in_sizes; (void)n_in; (void)out_size; (void)ws_size;
  const float* A      = (const float*)d_in[0];
  const float* X      = (const float*)d_in[1];
  const float* W_msg1 = (const float*)d_in[2];
  const float* b_msg1 = (const float*)d_in[3];
  const float* W_msg2 = (const float*)d_in[4];
  const float* b_msg2 = (const float*)d_in[5];
  const float* W_ir   = (const float*)d_in[6];
  const float* b_ir   = (const float*)d_in[7];
  const float* W_ii   = (const float*)d_in[8];
  const float* b_ii   = (const float*)d_in[9];
  const float* W_in   = (const float*)d_in[10];
  const float* b_in   = (const float*)d_in[11];
  const float* W_hr   = (const float*)d_in[12];
  const float* W_hi   = (const float*)d_in[13];
  const float* W_hh   = (const float*)d_in[14];
  const float* W_o1   = (const float*)d_in[15];
  const float* b_o1   = (const float*)d_in[16];
  const float* W_o2   = (const float*)d_in[17];
  const float* b_o2   = (const float*)d_in[18];
  const float* W_o3   = (const float*)d_in[19];
  const float* b_o3   = (const float*)d_in[20];
  const float* log_sigma = (const float*)d_in[21];
  float* ws  = (float*)d_ws;
  float* out = (float*)d_out;

  init_kernel<<<(INIT_TOTAL + 255) / 256, 256, 0, stream>>>(
      A, W_msg2, W_ir, W_ii, W_in, W_hr, W_hi, W_hh, W_o1, W_o2, W_o3, W_msg1, ws);
  step_all_kernel<<<NBLK, 256, 0, stream>>>(X, b_msg1, b_msg2, b_ir, b_ii, b_in, ws);
  out_kernel<<<NBLK, 256, 0, stream>>>(X, b_o1, b_o2, b_o3, ws, out);
  final_kernel<<<1, 256, 0, stream>>>(log_sigma, ws, out);
}

// Round 6
// 281.188 us; speedup vs baseline: 3.3221x; 1.2712x over previous
//
#include <hip/hip_runtime.h>

// Dims: B=4, T=16, N=128, D=16, H=64, MH=128, 15 steps. NBLK=512 persistent blocks.
#define NBLK 512

// ---- workspace float offsets ----
#define OFF_HS   0        // bf16 hs ping-pong: 2 * 65536 ushorts = 65536 floats
#define OFF_PART 65536    // 512 mse partials
#define OFF_SYNC 66048    // 512 ints: flag[b][j] = last completed step+1 (monotonic)
#define OFF_BF   66560    // bf16 weights: 49152 ushorts

// ---- bf16 (ushort) offsets within bf area ----
#define BW2F 0        // W_msg2 B-frags: 16*64*8 = 8192
#define BWIR 8192
#define BWII 9216
#define BWIN 10240
#define BWHR 11264
#define BWHI 15360
#define BWHH 19456
#define BWO1 23552    // O1|O2|O3 contiguous: 4096+4096+1024 = 9216
#define BWO2 27648
#define BWO3 31744
#define BW1S 32768    // W1s | W1r : 16384

#define INIT_TOTAL (32768 + 512 + 49152)

typedef __attribute__((ext_vector_type(8))) __bf16 bf16x8;
typedef __attribute__((ext_vector_type(4))) float f32x4;
union frag_u { bf16x8 v; unsigned short s[8]; int4 q; };
union ldu { int4 q; unsigned short s[8]; };

__device__ __forceinline__ unsigned short f2b(float x) {
  unsigned int u = __float_as_uint(x);
  u += 0x7fffu + ((u >> 16) & 1u);      // RNE
  return (unsigned short)(u >> 16);
}
__device__ __forceinline__ float b2f(unsigned short u) {
  return __uint_as_float(((unsigned int)u) << 16);
}
__device__ __forceinline__ float fast_tanh(float x) {
  float e = __builtin_amdgcn_exp2f(x * 2.8853900817779268f);
  return 1.0f - 2.0f * __builtin_amdgcn_rcpf(e + 1.0f);
}
__device__ __forceinline__ float fast_sigmoid(float x) {
  float e = __builtin_amdgcn_exp2f(x * -1.4426950408889634f);
  return __builtin_amdgcn_rcpf(1.0f + e);
}
__device__ __forceinline__ void st_coh_u32(unsigned* p, unsigned v) {
  __hip_atomic_store(p, v, __ATOMIC_RELAXED, __HIP_MEMORY_SCOPE_AGENT);
}
__device__ __forceinline__ void st_coh_i32(int* p, int v) {
  __hip_atomic_store(p, v, __ATOMIC_RELAXED, __HIP_MEMORY_SCOPE_AGENT);
}

// ---------------- init: hs0, flags, bf16 weight tables ----------------
__global__ void init_kernel(const float* __restrict__ W_msg2,
                            const float* __restrict__ W_ir, const float* __restrict__ W_ii,
                            const float* __restrict__ W_in,
                            const float* __restrict__ W_hr, const float* __restrict__ W_hi,
                            const float* __restrict__ W_hh,
                            const float* __restrict__ W_o1, const float* __restrict__ W_o2,
                            const float* __restrict__ W_o3,
                            const float* __restrict__ W_msg1, float* __restrict__ ws) {
  int idx = blockIdx.x * 256 + threadIdx.x;
  unsigned short* bw = (unsigned short*)(ws + OFF_BF);
  if (idx < 32768) { ws[OFF_HS + idx] = 0.0f; return; }   // hs parity-0 = 0 (bf16 zeros)
  idx -= 32768;
  if (idx < 512) { ((int*)(ws + OFF_SYNC))[idx] = 0; return; }  // flags
  idx -= 512;
  if (idx < 8192) {  // W_msg2 -> MFMA B-fragment order
    int f = idx >> 9, l = (idx >> 3) & 63, jj = idx & 7;
    int kc = f >> 2, nt = f & 3;
    int k = kc * 32 + ((l >> 4) << 3) + jj;
    int n = (nt << 4) + (l & 15);
    bw[BW2F + idx] = f2b(W_msg2[k * 64 + n]);
    return;
  }
  idx -= 8192;
  if (idx < 1024) { bw[BWIR + idx] = f2b(W_ir[idx]); return; }
  idx -= 1024;
  if (idx < 1024) { bw[BWII + idx] = f2b(W_ii[idx]); return; }
  idx -= 1024;
  if (idx < 1024) { bw[BWIN + idx] = f2b(W_in[idx]); return; }
  idx -= 1024;
  if (idx < 4096) { bw[BWHR + idx] = f2b(W_hr[idx]); return; }
  idx -= 4096;
  if (idx < 4096) { bw[BWHI + idx] = f2b(W_hi[idx]); return; }
  idx -= 4096;
  if (idx < 4096) { bw[BWHH + idx] = f2b(W_hh[idx]); return; }
  idx -= 4096;
  if (idx < 4096) { bw[BWO1 + idx] = f2b(W_o1[idx]); return; }
  idx -= 4096;
  if (idx < 4096) { bw[BWO2 + idx] = f2b(W_o2[idx]); return; }
  idx -= 4096;
  if (idx < 1024) { bw[BWO3 + idx] = f2b(W_o3[idx]); return; }
  idx -= 1024;
  if (idx < 16384) { bw[BW1S + idx] = f2b(W_msg1[idx]); return; }
}

// ---------------- persistent: all 15 steps + fused output MLP ----------------
__launch_bounds__(256, 2)
__global__ void step_all_kernel(const float* __restrict__ A, const float* __restrict__ X,
                                const float* __restrict__ b_msg1, const float* __restrict__ b_msg2,
                                const float* __restrict__ b_ir, const float* __restrict__ b_ii,
                                const float* __restrict__ b_in,
                                const float* __restrict__ b_o1, const float* __restrict__ b_o2,
                                const float* __restrict__ b_o3,
                                float* __restrict__ ws, float* __restrict__ out) {
  const int tid = threadIdx.x;
  const int bj = blockIdx.x;
  const int b = bj >> 7, j = bj & 127;
  const int wave = tid >> 6, lane = tid & 63;
  const unsigned short* bw = (const unsigned short*)(ws + OFF_BF);
  unsigned short* hs16 = (unsigned short*)(ws + OFF_HS);
  int* flags = (int*)(ws + OFF_SYNC);

  __shared__ unsigned short lds_gate[12288];  // W_hr@0 | W_hi@4096 | W_hh@8192
  __shared__ unsigned short lds_w1[16384];    // W1s@0 | W1r@8192
  __shared__ unsigned short lds_out[9216];    // W_o1@0 | W_o2@4096 | W_o3@8192
  __shared__ __align__(16) float sh_hr[128];  // hr row j — block-private
  __shared__ __align__(16) float sh_Ar[128];
  __shared__ float sh_aggw[4][64];
  __shared__ float sh_agg[64];
  __shared__ float sh_x[16];
  __shared__ float sh_hid[64];
  __shared__ float sh_pre[4][64];  // 3a: pre_r|pre_i|hh|pre_nx ; later reused by wave3 MLP
  __shared__ int sh_w01;           // monotonic hs-producer mini-barrier (waves 0,1)

  // ---- one-time staging ----
  {
    const int4* src = (const int4*)(bw + BWHR);   // 12288 ushorts = 1536 int4
    int4* dst = (int4*)lds_gate;
    for (int i = tid; i < 1536; i += 256) dst[i] = src[i];
    const int4* s2 = (const int4*)(bw + BW1S);    // 16384 ushorts = 2048 int4
    int4* d2 = (int4*)lds_w1;
    for (int i = tid; i < 2048; i += 256) d2[i] = s2[i];
    const int4* s3 = (const int4*)(bw + BWO1);    // 9216 ushorts = 1152 int4
    int4* d3 = (int4*)lds_out;
    for (int i = tid; i < 1152; i += 256) d3[i] = s3[i];
  }
  if (tid < 128) {
    // A_sym row j (symmetric -> col j): clip(0.5*(A[b,j,i]+A[b,i,j]),0,1), diag 0
    float a1 = A[(b << 14) + (j << 7) + tid];
    float a2 = A[(b << 14) + (tid << 7) + j];
    float v = 0.5f * (a1 + a2);
    v = (tid == j) ? 0.0f : v;
    sh_Ar[tid] = fminf(fmaxf(v, 0.0f), 1.0f);
    sh_hr[tid] = b_msg1[tid];                     // hr_0 = b_msg1
  } else if (tid < 192) {
    sh_hid[tid - 128] = 0.0f;
  }
  if (tid == 0) sh_w01 = 0;

  // persistent register state
  frag_u Bf[16];
  const int4* bw2 = (const int4*)bw;  // BW2F == 0
#pragma unroll
  for (int f = 0; f < 16; ++f) Bf[f].q = bw2[f * 64 + lane];
  float b2v[4];
#pragma unroll
  for (int nt = 0; nt < 4; ++nt) b2v[nt] = b_msg2[nt * 16 + (lane & 15)];
  float my_bias = 0.0f;
  if (wave == 0) my_bias = b_ir[lane];
  else if (wave == 1) my_bias = b_ii[lane];
  else if (wave == 3) my_bias = b_in[lane];
  const float bm1a = b_msg1[lane], bm1b = b_msg1[lane + 64];
  const float bo1 = b_o1[lane], bo2 = b_o2[lane];
  const float bo3 = (lane < 16) ? b_o3[lane] : 0.0f;
  float macc = 0.0f;  // wave3 lanes<16: mse partial

  const int lane15 = lane & 15;
  const int k0 = (lane >> 4) << 3;
  __syncthreads();

  for (int t = 0; t < 15; ++t) {
    const int par = t & 1;
    const unsigned short* hs_cur = hs16 + par * 65536;
    unsigned short* hs_nxt = hs16 + (par ^ 1) * 65536;

    if (tid < 16) sh_x[tid] = X[(((b << 4) + t) << 11) + (j << 4) + tid];

    // ---- phase 2: coherent bf16 hs loads (8 x dwordx4 per lane, two base regs) ----
    ldu va[8];  // [kc] = c0, [4+kc] = c1
    {
      const unsigned short* p0 = hs_cur + (((b << 7) + (wave << 5) + lane15) << 7) + k0;
      const unsigned short* p1 = p0 + 2048;  // +16 rows (4096 B — exceeds 13-bit imm)
      asm volatile(
          "global_load_dwordx4 %0, %8, off sc0 sc1\n\t"
          "global_load_dwordx4 %1, %8, off offset:64 sc0 sc1\n\t"
          "global_load_dwordx4 %2, %8, off offset:128 sc0 sc1\n\t"
          "global_load_dwordx4 %3, %8, off offset:192 sc0 sc1\n\t"
          "global_load_dwordx4 %4, %9, off sc0 sc1\n\t"
          "global_load_dwordx4 %5, %9, off offset:64 sc0 sc1\n\t"
          "global_load_dwordx4 %6, %9, off offset:128 sc0 sc1\n\t"
          "global_load_dwordx4 %7, %9, off offset:192 sc0 sc1\n\t"
          "s_waitcnt vmcnt(0)"
          : "=&v"(va[0].q), "=&v"(va[1].q), "=&v"(va[2].q), "=&v"(va[3].q),
            "=&v"(va[4].q), "=&v"(va[5].q), "=&v"(va[6].q), "=&v"(va[7].q)
          : "v"(p0), "v"(p1)
          : "memory");
    }

    float part[4] = {0.f, 0.f, 0.f, 0.f};
#pragma unroll
    for (int c = 0; c < 2; ++c) {
      f32x4 acc[4];
#pragma unroll
      for (int nt = 0; nt < 4; ++nt) acc[nt] = (f32x4){0.f, 0.f, 0.f, 0.f};
#pragma unroll
      for (int kc = 0; kc < 4; ++kc) {
        const ldu& u = va[c * 4 + kc];
        const float* hp = sh_hr + kc * 32 + k0;
        frag_u Af;
#pragma unroll
        for (int e = 0; e < 8; ++e)
          Af.s[e] = f2b(fast_tanh(b2f(u.s[e]) + hp[e]));
#pragma unroll
        for (int nt = 0; nt < 4; ++nt)
          acc[nt] = __builtin_amdgcn_mfma_f32_16x16x32_bf16(Af.v, Bf[kc * 4 + nt].v, acc[nt], 0, 0, 0);
      }
      const int ibase = ((wave << 1) + c) << 4;
      float4 aw = *(const float4*)(sh_Ar + ibase + ((lane >> 4) << 2));
#pragma unroll
      for (int r = 0; r < 4; ++r) {
        float wv = (r == 0) ? aw.x : (r == 1) ? aw.y : (r == 2) ? aw.z : aw.w;
#pragma unroll
        for (int nt = 0; nt < 4; ++nt)
          part[nt] += wv * fast_tanh(acc[nt][r] + b2v[nt]);
      }
    }
#pragma unroll
    for (int nt = 0; nt < 4; ++nt) {
      part[nt] += __shfl_xor(part[nt], 16);
      part[nt] += __shfl_xor(part[nt], 32);
    }
    if (lane < 16) {
#pragma unroll
      for (int nt = 0; nt < 4; ++nt) sh_aggw[wave][nt * 16 + lane] = part[nt];
    }
    __syncthreads();
    if (tid < 64)
      sh_agg[tid] = sh_aggw[0][tid] + sh_aggw[1][tid] + sh_aggw[2][tid] + sh_aggw[3][tid];
    __syncthreads();

    // ---- phase 3a: 4-wave parallel gate matvecs ----
    {
      const int h = lane;
      float s = my_bias;
      if (wave == 3) {
#pragma unroll
        for (int d = 0; d < 16; ++d) s += sh_x[d] * b2f(bw[BWIN + d * 64 + h]);
      } else {
        if (wave < 2) {
          const int xoff = (wave == 0) ? BWIR : BWII;
#pragma unroll
          for (int d = 0; d < 16; ++d) s += sh_x[d] * b2f(bw[xoff + d * 64 + h]);
        }
        const int woff = wave * 4096;  // HR@0 HI@4096 HH@8192
        for (int k = 0; k < 64; ++k) s += sh_agg[k] * b2f(lds_gate[woff + k * 64 + h]);
      }
      sh_pre[wave][h] = s;
    }
    __syncthreads();
    if (tid < 64) {
      float r  = fast_sigmoid(sh_pre[0][tid]);
      float ig = fast_sigmoid(sh_pre[1][tid]);
      float n  = fast_tanh(sh_pre[3][tid] + r * sh_pre[2][tid]);
      sh_hid[tid] = (1.0f - ig) * n + ig * sh_hid[tid];
    }
    __syncthreads();

    // ---- wave-specialized tail ----
    if (wave == 3) {
      // fused output MLP + pred + mse (wave-synchronous; off inter-block critical path)
      float s = bo1;
      for (int k = 0; k < 64; ++k) s += sh_hid[k] * b2f(lds_out[k * 64 + lane]);
      sh_pre[0][lane] = fmaxf(s, 0.0f);
      s = bo2;
      for (int k = 0; k < 64; ++k) s += sh_pre[0][k] * b2f(lds_out[4096 + k * 64 + lane]);
      sh_pre[1][lane] = fmaxf(s, 0.0f);
      if (lane < 16) {
        float s3 = bo3;
        for (int k = 0; k < 64; ++k) s3 += sh_pre[1][k] * b2f(lds_out[8192 + (k << 4) + lane]);
        float pred = sh_x[lane] + s3;
        out[((b * 15 + t) * 128 + j) * 16 + lane] = pred;
        float d = X[(((b << 4) + t + 1) << 11) + (j << 4) + lane] - pred;
        macc += d * d;
      }
    } else if (t < 14) {
      if (wave <= 1) {
        // next hs (cross-block): 128 outputs over waves 0,1; bf16-packed coherent stores
        const int m = tid;  // 0..127
        float s = 0.0f;
        for (int h = 0; h < 64; ++h) s += sh_hid[h] * b2f(lds_w1[h * 128 + m]);
        float hi = __shfl_down(s, 1);
        if (!(lane & 1)) {
          unsigned pk = ((unsigned)f2b(hi) << 16) | (unsigned)f2b(s);
          st_coh_u32((unsigned*)hs_nxt + (bj << 6) + (m >> 1), pk);
        }
        asm volatile("s_waitcnt vmcnt(0)" ::: "memory");  // hs stores at coherence point
        if (lane == 0) atomicAdd(&sh_w01, 1);
        if (wave == 0) {
          const int tgt = t + 1;
          if (lane == 0) {
            while (__hip_atomic_load(&sh_w01, __ATOMIC_RELAXED, __HIP_MEMORY_SCOPE_WORKGROUP) < 2 * tgt) {}
            st_coh_i32(flags + (b << 7) + j, tgt);  // single-store arrival
          }
          // whole wave polls all 128 flags of this batch (2 per lane)
          const int* fp = flags + (b << 7) + (lane << 1);
          int2 fv;
          do {
            asm volatile("global_load_dwordx2 %0, %1, off sc0 sc1\n\ts_waitcnt vmcnt(0)"
                         : "=v"(fv) : "v"(fp) : "memory");
          } while (__any(fv.x < tgt || fv.y < tgt));
        }
      } else {
        // wave 2: next hr (block-private, off inter-block critical path)
        float s1 = bm1a, s2 = bm1b;
        for (int h = 0; h < 64; ++h) {
          float hv = sh_hid[h];
          s1 += hv * b2f(lds_w1[8192 + h * 128 + lane]);
          s2 += hv * b2f(lds_w1[8192 + h * 128 + lane + 64]);
        }
        sh_hr[lane] = s1;
        sh_hr[lane + 64] = s2;
      }
    }
    __syncthreads();
  }

  // mse partial: wave3 lanes 0..15 hold per-d sums
  if (wave == 3) {
    macc += __shfl_xor(macc, 1);
    macc += __shfl_xor(macc, 2);
    macc += __shfl_xor(macc, 4);
    macc += __shfl_xor(macc, 8);
    if (lane == 0) ws[OFF_PART + bj] = macc;
  }
}

// ---------------- finalize: loglik ----------------
__global__ void final_kernel(const float* __restrict__ log_sigma, const float* __restrict__ ws,
                             float* __restrict__ out) {
  __shared__ float red[256];
  const int tid = threadIdx.x;
  red[tid] = ws[OFF_PART + tid] + ws[OFF_PART + 256 + tid];
  __syncthreads();
  if (tid == 0) {
    float mse = 0.0f;
    for (int i = 0; i < 256; ++i) mse += red[i];
    float sigma = expf(log_sigma[0]);
    float cst = 8192.0f * logf(sigma * sqrtf(6.2831853071795864f));  // N*D*B
    out[122880] = -(mse / (2.0f * sigma * sigma) + 15.0f * cst);
  }
}

extern "C" void kernel_launch(void* const* d_in, const int* in_sizes, int n_in,
                              void* d_out, int out_size, void* d_ws, size_t ws_size,
                              hipStream_t stream) {
  (void)in_sizes; (void)n_in; (void)out_size; (void)ws_size;
  const float* A      = (const float*)d_in[0];
  const float* X      = (const float*)d_in[1];
  const float* W_msg1 = (const float*)d_in[2];
  const float* b_msg1 = (const float*)d_in[3];
  const float* W_msg2 = (const float*)d_in[4];
  const float* b_msg2 = (const float*)d_in[5];
  const float* W_ir   = (const float*)d_in[6];
  const float* b_ir   = (const float*)d_in[7];
  const float* W_ii   = (const float*)d_in[8];
  const float* b_ii   = (const float*)d_in[9];
  const float* W_in   = (const float*)d_in[10];
  const float* b_in   = (const float*)d_in[11];
  const float* W_hr   = (const float*)d_in[12];
  const float* W_hi   = (const float*)d_in[13];
  const float* W_hh   = (const float*)d_in[14];
  const float* W_o1   = (const float*)d_in[15];
  const float* b_o1   = (const float*)d_in[16];
  const float* W_o2   = (const float*)d_in[17];
  const float* b_o2   = (const float*)d_in[18];
  const float* W_o3   = (const float*)d_in[19];
  const float* b_o3   = (const float*)d_in[20];
  const float* log_sigma = (const float*)d_in[21];
  float* ws  = (float*)d_ws;
  float* out = (float*)d_out;

  init_kernel<<<(INIT_TOTAL + 255) / 256, 256, 0, stream>>>(
      W_msg2, W_ir, W_ii, W_in, W_hr, W_hi, W_hh, W_o1, W_o2, W_o3, W_msg1, ws);
  step_all_kernel<<<NBLK, 256, 0, stream>>>(A, X, b_msg1, b_msg2, b_ir, b_ii, b_in,
                                            b_o1, b_o2, b_o3, ws, out);
  final_kernel<<<1, 256, 0, stream>>>(log_sigma, ws, out);
}

// Round 8
// 262.883 us; speedup vs baseline: 3.5534x; 1.0696x over previous
//
#include <hip/hip_runtime.h>

// Dims: B=4, T=16, N=128, D=16, H=64, MH=128, 15 steps. NBLK=512 persistent blocks.
#define NBLK 512
#define CSCALE 2.8853900817779268f   // 2/ln2: tanh(x) = 1 - 2/(exp2(x*CSCALE)+1)

// ---- workspace float offsets ----
#define OFF_HS   0        // bf16 hs ping-pong: 2 * 65536 ushorts (PRESCALED by CSCALE)
#define OFF_PART 65536    // 512 mse partials
#define OFF_SYNC 66048    // 512 ints: flag[b][j] = last completed step+1 (monotonic)
#define OFF_BF   66560    // bf16 weights: 57344 ushorts

// ---- bf16 (ushort) offsets within bf area ----
#define BW2F  0        // W_msg2 B-frags (PRESCALED): 16*64*8 = 8192
#define BWIR  8192
#define BWII  9216
#define BWIN  10240
#define BWHR  11264    // HR|HI|HH contiguous 12288
#define BWHI  15360
#define BWHH  19456
#define BWO1  23552    // O1|O2|O3 contiguous 9216
#define BWO2  27648
#define BWO3  31744
#define BW1S  32768    // W1s | W1r : 16384
#define BW1RT 49152    // W1r TRANSPOSED [m][h]: 8192

#define INIT_TOTAL (32768 + 512 + 49152 + 8192)

typedef __attribute__((ext_vector_type(8))) __bf16 bf16x8;
typedef __attribute__((ext_vector_type(4))) float f32x4;
union frag_u { bf16x8 v; unsigned short s[8]; int4 q; };
union ldu { int4 q; unsigned short s[8]; unsigned u[4]; };

__device__ __forceinline__ unsigned short f2b(float x) {
  unsigned int u = __float_as_uint(x);
  u += 0x7fffu + ((u >> 16) & 1u);      // RNE (init only)
  return (unsigned short)(u >> 16);
}
__device__ __forceinline__ float b2f(unsigned short u) {
  return __uint_as_float(((unsigned int)u) << 16);
}
__device__ __forceinline__ float fast_tanh(float x) {        // raw-input tanh
  float e = __builtin_amdgcn_exp2f(x * CSCALE);
  return 1.0f - 2.0f * __builtin_amdgcn_rcpf(e + 1.0f);
}
__device__ __forceinline__ float tanh_pre(float x) {         // x already * CSCALE
  float e = __builtin_amdgcn_exp2f(x);
  return 1.0f - 2.0f * __builtin_amdgcn_rcpf(e + 1.0f);
}
__device__ __forceinline__ float fast_sigmoid(float x) {
  float e = __builtin_amdgcn_exp2f(x * -1.4426950408889634f);
  return __builtin_amdgcn_rcpf(1.0f + e);
}
// pack two floats -> bf16x2 (round-nearest ties-away) in ~3 VALU
__device__ __forceinline__ unsigned pack_bf2(float lo, float hi) {
  unsigned a = __float_as_uint(lo) + 0x8000u;
  unsigned b = __float_as_uint(hi) + 0x8000u;
  return __builtin_amdgcn_perm(b, a, 0x07060302u);  // {b.hi16, a.hi16}
}
__device__ __forceinline__ void st_coh_u32(unsigned* p, unsigned v) {
  __hip_atomic_store(p, v, __ATOMIC_RELAXED, __HIP_MEMORY_SCOPE_AGENT);
}
__device__ __forceinline__ void st_coh_i32(int* p, int v) {
  __hip_atomic_store(p, v, __ATOMIC_RELAXED, __HIP_MEMORY_SCOPE_AGENT);
}

// ---------------- init: hs0, flags, bf16 weight tables ----------------
__global__ void init_kernel(const float* __restrict__ W_msg2,
                            const float* __restrict__ W_ir, const float* __restrict__ W_ii,
                            const float* __restrict__ W_in,
                            const float* __restrict__ W_hr, const float* __restrict__ W_hi,
                            const float* __restrict__ W_hh,
                            const float* __restrict__ W_o1, const float* __restrict__ W_o2,
                            const float* __restrict__ W_o3,
                            const float* __restrict__ W_msg1, float* __restrict__ ws) {
  int idx = blockIdx.x * 256 + threadIdx.x;
  unsigned short* bw = (unsigned short*)(ws + OFF_BF);
  if (idx < 32768) { ws[OFF_HS + idx] = 0.0f; return; }   // hs parity-0 = 0 (bf16 zeros)
  idx -= 32768;
  if (idx < 512) { ((int*)(ws + OFF_SYNC))[idx] = 0; return; }  // flags
  idx -= 512;
  if (idx < 8192) {  // W_msg2 -> MFMA B-fragment order, PRESCALED by CSCALE
    int f = idx >> 9, l = (idx >> 3) & 63, jj = idx & 7;
    int kc = f >> 2, nt = f & 3;
    int k = kc * 32 + ((l >> 4) << 3) + jj;
    int n = (nt << 4) + (l & 15);
    bw[BW2F + idx] = f2b(W_msg2[k * 64 + n] * CSCALE);
    return;
  }
  idx -= 8192;
  if (idx < 1024) { bw[BWIR + idx] = f2b(W_ir[idx]); return; }
  idx -= 1024;
  if (idx < 1024) { bw[BWII + idx] = f2b(W_ii[idx]); return; }
  idx -= 1024;
  if (idx < 1024) { bw[BWIN + idx] = f2b(W_in[idx]); return; }
  idx -= 1024;
  if (idx < 4096) { bw[BWHR + idx] = f2b(W_hr[idx]); return; }
  idx -= 4096;
  if (idx < 4096) { bw[BWHI + idx] = f2b(W_hi[idx]); return; }
  idx -= 4096;
  if (idx < 4096) { bw[BWHH + idx] = f2b(W_hh[idx]); return; }
  idx -= 4096;
  if (idx < 4096) { bw[BWO1 + idx] = f2b(W_o1[idx]); return; }
  idx -= 4096;
  if (idx < 4096) { bw[BWO2 + idx] = f2b(W_o2[idx]); return; }
  idx -= 4096;
  if (idx < 1024) { bw[BWO3 + idx] = f2b(W_o3[idx]); return; }
  idx -= 1024;
  if (idx < 16384) { bw[BW1S + idx] = f2b(W_msg1[idx]); return; }  // W1s|W1r linear
  idx -= 16384;
  if (idx < 8192) {  // W1r transposed: bwt[m*64+h] = W_msg1[(64+h)*128+m]
    int m = idx >> 6, h = idx & 63;
    bw[BW1RT + idx] = f2b(W_msg1[(64 + h) * 128 + m]);
    return;
  }
}

// ---------------- persistent: all 15 steps + fused output MLP ----------------
__launch_bounds__(256, 2)
__global__ void step_all_kernel(const float* __restrict__ A, const float* __restrict__ X,
                                const float* __restrict__ b_msg1, const float* __restrict__ b_msg2,
                                const float* __restrict__ b_ir, const float* __restrict__ b_ii,
                                const float* __restrict__ b_in,
                                const float* __restrict__ b_o1, const float* __restrict__ b_o2,
                                const float* __restrict__ b_o3,
                                float* __restrict__ ws, float* __restrict__ out) {
  const int tid = threadIdx.x;
  const int bj = blockIdx.x;
  const int b = bj >> 7, j = bj & 127;
  const int wave = tid >> 6, lane = tid & 63;
  const unsigned short* bw = (const unsigned short*)(ws + OFF_BF);
  unsigned short* hs16 = (unsigned short*)(ws + OFF_HS);
  int* flags = (int*)(ws + OFF_SYNC);

  // transposed, padded (stride 68) weight tables
  __shared__ __align__(16) unsigned short lds_gate_t[3 * 64 * 68];  // [g][h][k]
  __shared__ __align__(16) unsigned short lds_w1t[128 * 68];        // W1s^T [m][h]
  __shared__ __align__(16) unsigned short lds_outt[2 * 64 * 68 + 16 * 68];  // O1^T|O2^T|O3^T
  __shared__ __align__(16) float sh_hr[128];   // hr row j, PRESCALED — block-private
  __shared__ __align__(16) float sh_Ar[128];
  __shared__ __align__(16) float sh_aggw[4][64];
  __shared__ __align__(16) float sh_agg[64];
  __shared__ __align__(16) float sh_xall[256]; // all 16 X rows for (b,j)
  __shared__ __align__(16) float sh_hid[64];
  __shared__ __align__(16) float sh_pre[4][64];
  __shared__ int sh_w01;

  // ---- one-time staging ----
  for (int i = tid; i < 12288; i += 256) {   // gates -> [g][h][k]
    int g = i >> 12, r = i & 4095, k = r >> 6, h = r & 63;
    lds_gate_t[g * 4352 + h * 68 + k] = bw[BWHR + i];
  }
  for (int i = tid; i < 8192; i += 256) {    // W1s -> [m][h]
    int h = i >> 7, m = i & 127;
    lds_w1t[m * 68 + h] = bw[BW1S + i];
  }
  for (int i = tid; i < 8192; i += 256) {    // O1,O2 -> [o][h][k]
    int o = i >> 12, r = i & 4095, k = r >> 6, h = r & 63;
    lds_outt[o * 4352 + h * 68 + k] = bw[BWO1 + i];
  }
  for (int i = tid; i < 1024; i += 256) {    // O3 -> [d][k]
    int k = i >> 4, d = i & 15;
    lds_outt[8704 + d * 68 + k] = bw[BWO3 + i];
  }
  {
    int t0 = tid >> 4, d = tid & 15;
    sh_xall[tid] = X[(((b << 4) + t0) << 11) + (j << 4) + d];
  }
  if (tid < 128) {
    float a1 = A[(b << 14) + (j << 7) + tid];
    float a2 = A[(b << 14) + (tid << 7) + j];
    float v = 0.5f * (a1 + a2);
    v = (tid == j) ? 0.0f : v;
    sh_Ar[tid] = fminf(fmaxf(v, 0.0f), 1.0f);
    sh_hr[tid] = b_msg1[tid] * CSCALE;            // hr_0 = b_msg1, prescaled
  } else if (tid < 192) {
    sh_hid[tid - 128] = 0.0f;
  }
  if (tid == 0) sh_w01 = 0;

  // persistent register state
  frag_u Bf[16];
  const int4* bw2 = (const int4*)bw;  // BW2F == 0
#pragma unroll
  for (int f = 0; f < 16; ++f) Bf[f].q = bw2[f * 64 + lane];
  float b2v[4];
#pragma unroll
  for (int nt = 0; nt < 4; ++nt) b2v[nt] = b_msg2[nt * 16 + (lane & 15)] * CSCALE;
  float my_bias = 0.0f;
  float wx[16];
  if (wave != 2) {
    my_bias = (wave == 0) ? b_ir[lane] : (wave == 1) ? b_ii[lane] : b_in[lane];
    const int xo = (wave == 0) ? BWIR : (wave == 1) ? BWII : BWIN;
#pragma unroll
    for (int d = 0; d < 16; ++d) wx[d] = b2f(bw[xo + d * 64 + lane]);
  }
  const float bm1a = b_msg1[lane], bm1b = b_msg1[lane + 64];
  const float bo1 = b_o1[lane], bo2 = b_o2[lane];
  const float bo3 = (lane < 16) ? b_o3[lane] : 0.0f;
  float macc = 0.0f;

  const int lane15 = lane & 15;
  const int k0 = (lane >> 4) << 3;
  __syncthreads();

  for (int t = 0; t < 15; ++t) {
    const int par = t & 1;
    const unsigned short* hs_cur = hs16 + par * 65536;
    unsigned short* hs_nxt = hs16 + (par ^ 1) * 65536;

    // ---- phase 2: coherent bf16 hs loads (single asm block, proven pattern) ----
    ldu va[8];
    {
      const unsigned short* p0 = hs_cur + (((b << 7) + (wave << 5) + lane15) << 7) + k0;
      const unsigned short* p1 = p0 + 2048;
      asm volatile(
          "global_load_dwordx4 %0, %8, off sc0 sc1\n\t"
          "global_load_dwordx4 %1, %8, off offset:64 sc0 sc1\n\t"
          "global_load_dwordx4 %2, %8, off offset:128 sc0 sc1\n\t"
          "global_load_dwordx4 %3, %8, off offset:192 sc0 sc1\n\t"
          "global_load_dwordx4 %4, %9, off sc0 sc1\n\t"
          "global_load_dwordx4 %5, %9, off offset:64 sc0 sc1\n\t"
          "global_load_dwordx4 %6, %9, off offset:128 sc0 sc1\n\t"
          "global_load_dwordx4 %7, %9, off offset:192 sc0 sc1\n\t"
          "s_waitcnt vmcnt(0)"
          : "=&v"(va[0].q), "=&v"(va[1].q), "=&v"(va[2].q), "=&v"(va[3].q),
            "=&v"(va[4].q), "=&v"(va[5].q), "=&v"(va[6].q), "=&v"(va[7].q)
          : "v"(p0), "v"(p1)
          : "memory");
    }

    float part[4] = {0.f, 0.f, 0.f, 0.f};
#pragma unroll
    for (int c = 0; c < 2; ++c) {
      f32x4 acc[4];
#pragma unroll
      for (int nt = 0; nt < 4; ++nt) acc[nt] = (f32x4){0.f, 0.f, 0.f, 0.f};
#pragma unroll
      for (int kc = 0; kc < 4; ++kc) {
        const ldu& u = va[c * 4 + kc];
        const float* hp = sh_hr + kc * 32 + k0;
        frag_u Af;
        int* ap = (int*)&Af.q;
#pragma unroll
        for (int p = 0; p < 4; ++p) {
          unsigned w = u.u[p];
          float x0 = __uint_as_float(w << 16) + hp[2 * p];        // prescaled sum
          float x1 = __uint_as_float(w & 0xffff0000u) + hp[2 * p + 1];
          ap[p] = (int)pack_bf2(tanh_pre(x0), tanh_pre(x1));
        }
#pragma unroll
        for (int nt = 0; nt < 4; ++nt)
          acc[nt] = __builtin_amdgcn_mfma_f32_16x16x32_bf16(Af.v, Bf[kc * 4 + nt].v, acc[nt], 0, 0, 0);
      }
      const int ibase = ((wave << 1) + c) << 4;
      float4 aw = *(const float4*)(sh_Ar + ibase + ((lane >> 4) << 2));
#pragma unroll
      for (int r = 0; r < 4; ++r) {
        float wv = (r == 0) ? aw.x : (r == 1) ? aw.y : (r == 2) ? aw.z : aw.w;
#pragma unroll
        for (int nt = 0; nt < 4; ++nt)
          part[nt] += wv * tanh_pre(acc[nt][r] + b2v[nt]);   // acc,b2v prescaled
      }
    }
#pragma unroll
    for (int nt = 0; nt < 4; ++nt) {
      part[nt] += __shfl_xor(part[nt], 16);
      part[nt] += __shfl_xor(part[nt], 32);
    }
    if (lane < 16) {
#pragma unroll
      for (int nt = 0; nt < 4; ++nt) sh_aggw[wave][nt * 16 + lane] = part[nt];
    }
    __syncthreads();
    if (tid < 64)
      sh_agg[tid] = sh_aggw[0][tid] + sh_aggw[1][tid] + sh_aggw[2][tid] + sh_aggw[3][tid];
    __syncthreads();

    // ---- phase 3a: gate matvecs (transposed rows, split accumulators) ----
    {
      float s = 0.0f;
      if (wave != 2) {
        s = my_bias;
        const float4* xr = (const float4*)(sh_xall + (t << 4));
#pragma unroll
        for (int c = 0; c < 4; ++c) {
          float4 xv = xr[c];
          s += xv.x * wx[4 * c] + xv.y * wx[4 * c + 1] + xv.z * wx[4 * c + 2] + xv.w * wx[4 * c + 3];
        }
      }
      if (wave != 3) {
        const ushort4* row = (const ushort4*)(lds_gate_t + wave * 4352 + lane * 68);
        const float4* ag = (const float4*)sh_agg;
        float a0 = s, a1 = 0.f, a2 = 0.f, a3 = 0.f;
#pragma unroll
        for (int c = 0; c < 16; ++c) {
          ushort4 wv = row[c];
          float4 av = ag[c];
          a0 += av.x * b2f(wv.x); a1 += av.y * b2f(wv.y);
          a2 += av.z * b2f(wv.z); a3 += av.w * b2f(wv.w);
        }
        s = (a0 + a1) + (a2 + a3);
      }
      sh_pre[wave][lane] = s;
    }
    __syncthreads();
    if (tid < 64) {
      float r  = fast_sigmoid(sh_pre[0][tid]);
      float ig = fast_sigmoid(sh_pre[1][tid]);
      float n  = fast_tanh(sh_pre[3][tid] + r * sh_pre[2][tid]);
      sh_hid[tid] = (1.0f - ig) * n + ig * sh_hid[tid];
    }
    __syncthreads();

    // ---- wave-specialized tail ----
    if (wave == 3) {
      // fused output MLP + pred + mse
      const float4* h4 = (const float4*)sh_hid;
      {
        const ushort4* r1 = (const ushort4*)(lds_outt + lane * 68);
        float a0 = bo1, a1 = 0.f, a2 = 0.f, a3 = 0.f;
#pragma unroll
        for (int c = 0; c < 16; ++c) {
          ushort4 wv = r1[c]; float4 hv = h4[c];
          a0 += hv.x * b2f(wv.x); a1 += hv.y * b2f(wv.y);
          a2 += hv.z * b2f(wv.z); a3 += hv.w * b2f(wv.w);
        }
        sh_pre[0][lane] = fmaxf((a0 + a1) + (a2 + a3), 0.0f);
      }
      {
        const ushort4* r2 = (const ushort4*)(lds_outt + 4352 + lane * 68);
        const float4* p4 = (const float4*)sh_pre[0];
        float a0 = bo2, a1 = 0.f, a2 = 0.f, a3 = 0.f;
#pragma unroll
        for (int c = 0; c < 16; ++c) {
          ushort4 wv = r2[c]; float4 pv = p4[c];
          a0 += pv.x * b2f(wv.x); a1 += pv.y * b2f(wv.y);
          a2 += pv.z * b2f(wv.z); a3 += pv.w * b2f(wv.w);
        }
        sh_pre[1][lane] = fmaxf((a0 + a1) + (a2 + a3), 0.0f);
      }
      if (lane < 16) {
        const ushort4* r3 = (const ushort4*)(lds_outt + 8704 + lane * 68);
        const float4* q4 = (const float4*)sh_pre[1];
        float a0 = bo3, a1 = 0.f, a2 = 0.f, a3 = 0.f;
#pragma unroll
        for (int c = 0; c < 16; ++c) {
          ushort4 wv = r3[c]; float4 qv = q4[c];
          a0 += qv.x * b2f(wv.x); a1 += qv.y * b2f(wv.y);
          a2 += qv.z * b2f(wv.z); a3 += qv.w * b2f(wv.w);
        }
        float pred = sh_xall[(t << 4) + lane] + (a0 + a1) + (a2 + a3);
        out[((b * 15 + t) * 128 + j) * 16 + lane] = pred;
        float d = sh_xall[((t + 1) << 4) + lane] - pred;
        macc += d * d;
      }
    } else if (t < 14) {
      if (wave <= 1) {
        // next hs (cross-block): transposed W1s rows, prescaled output
        const int m = tid;  // 0..127
        const ushort4* row = (const ushort4*)(lds_w1t + m * 68);
        const float4* h4 = (const float4*)sh_hid;
        float a0 = 0.f, a1 = 0.f, a2 = 0.f, a3 = 0.f;
#pragma unroll
        for (int c = 0; c < 16; ++c) {
          ushort4 wv = row[c]; float4 hv = h4[c];
          a0 += hv.x * b2f(wv.x); a1 += hv.y * b2f(wv.y);
          a2 += hv.z * b2f(wv.z); a3 += hv.w * b2f(wv.w);
        }
        float s = ((a0 + a1) + (a2 + a3)) * CSCALE;
        float hi = __shfl_down(s, 1);
        if (!(lane & 1))
          st_coh_u32((unsigned*)hs_nxt + (bj << 6) + (m >> 1), pack_bf2(s, hi));
        asm volatile("s_waitcnt vmcnt(0)" ::: "memory");
        if (lane == 0) atomicAdd(&sh_w01, 1);
        if (wave == 0) {
          const int tgt = t + 1;
          if (lane == 0) {
            while (__hip_atomic_load(&sh_w01, __ATOMIC_RELAXED, __HIP_MEMORY_SCOPE_WORKGROUP) < 2 * tgt) {}
            st_coh_i32(flags + (b << 7) + j, tgt);
          }
          const int* fp = flags + (b << 7) + (lane << 1);
          int2 fv;
          do {
            asm volatile("global_load_dwordx2 %0, %1, off sc0 sc1\n\ts_waitcnt vmcnt(0)"
                         : "=v"(fv) : "v"(fp) : "memory");
          } while (__any(fv.x < tgt || fv.y < tgt));
        }
      } else {
        // wave 2: next hr from transposed W1r in L2 (off critical path), prescaled
        const int4* wp1 = (const int4*)(bw + BW1RT + (lane << 6));
        const int4* wp2 = (const int4*)(bw + BW1RT + ((lane + 64) << 6));
        const float4* h4 = (const float4*)sh_hid;
        float s1a = bm1a, s1b = 0.f, s2a = bm1b, s2b = 0.f;
#pragma unroll
        for (int c = 0; c < 8; ++c) {
          ldu u1, u2; u1.q = wp1[c]; u2.q = wp2[c];
          float4 h0 = h4[2 * c], h1 = h4[2 * c + 1];
          s1a += h0.x * b2f(u1.s[0]); s1b += h0.y * b2f(u1.s[1]);
          s1a += h0.z * b2f(u1.s[2]); s1b += h0.w * b2f(u1.s[3]);
          s1a += h1.x * b2f(u1.s[4]); s1b += h1.y * b2f(u1.s[5]);
          s1a += h1.z * b2f(u1.s[6]); s1b += h1.w * b2f(u1.s[7]);
          s2a += h0.x * b2f(u2.s[0]); s2b += h0.y * b2f(u2.s[1]);
          s2a += h0.z * b2f(u2.s[2]); s2b += h0.w * b2f(u2.s[3]);
          s2a += h1.x * b2f(u2.s[4]); s2b += h1.y * b2f(u2.s[5]);
          s2a += h1.z * b2f(u2.s[6]); s2b += h1.w * b2f(u2.s[7]);
        }
        sh_hr[lane] = (s1a + s1b) * CSCALE;
        sh_hr[lane + 64] = (s2a + s2b) * CSCALE;
      }
    }
    __syncthreads();
  }

  if (wave == 3) {
    macc += __shfl_xor(macc, 1);
    macc += __shfl_xor(macc, 2);
    macc += __shfl_xor(macc, 4);
    macc += __shfl_xor(macc, 8);
    if (lane == 0) ws[OFF_PART + bj] = macc;
  }
}

// ---------------- finalize: loglik ----------------
__global__ void final_kernel(const float* __restrict__ log_sigma, const float* __restrict__ ws,
                             float* __restrict__ out) {
  __shared__ float red[256];
  const int tid = threadIdx.x;
  red[tid] = ws[OFF_PART + tid] + ws[OFF_PART + 256 + tid];
  __syncthreads();
  if (tid == 0) {
    float mse = 0.0f;
    for (int i = 0; i < 256; ++i) mse += red[i];
    float sigma = expf(log_sigma[0]);
    float cst = 8192.0f * logf(sigma * sqrtf(6.2831853071795864f));  // N*D*B
    out[122880] = -(mse / (2.0f * sigma * sigma) + 15.0f * cst);
  }
}

extern "C" void kernel_launch(void* const* d_in, const int* in_sizes, int n_in,
                              void* d_out, int out_size, void* d_ws, size_t ws_size,
                              hipStream_t stream) {
  (void)in_sizes; (void)n_in; (void)out_size; (void)ws_size;
  const float* A      = (const float*)d_in[0];
  const float* X      = (const float*)d_in[1];
  const float* W_msg1 = (const float*)d_in[2];
  const float* b_msg1 = (const float*)d_in[3];
  const float* W_msg2 = (const float*)d_in[4];
  const float* b_msg2 = (const float*)d_in[5];
  const float* W_ir   = (const float*)d_in[6];
  const float* b_ir   = (const float*)d_in[7];
  const float* W_ii   = (const float*)d_in[8];
  const float* b_ii   = (const float*)d_in[9];
  const float* W_in   = (const float*)d_in[10];
  const float* b_in   = (const float*)d_in[11];
  const float* W_hr   = (const float*)d_in[12];
  const float* W_hi   = (const float*)d_in[13];
  const float* W_hh   = (const float*)d_in[14];
  const float* W_o1   = (const float*)d_in[15];
  const float* b_o1   = (const float*)d_in[16];
  const float* W_o2   = (const float*)d_in[17];
  const float* b_o2   = (const float*)d_in[18];
  const float* W_o3   = (const float*)d_in[19];
  const float* b_o3   = (const float*)d_in[20];
  const float* log_sigma = (const float*)d_in[21];
  float* ws  = (float*)d_ws;
  float* out = (float*)d_out;

  init_kernel<<<(INIT_TOTAL + 255) / 256, 256, 0, stream>>>(
      W_msg2, W_ir, W_ii, W_in, W_hr, W_hi, W_hh, W_o1, W_o2, W_o3, W_msg1, ws);
  step_all_kernel<<<NBLK, 256, 0, stream>>>(A, X, b_msg1, b_msg2, b_ir, b_ii, b_in,
                                            b_o1, b_o2, b_o3, ws, out);
  final_kernel<<<1, 256, 0, stream>>>(log_sigma, ws, out);
}